// Round 18
// baseline (1357.633 us; speedup 1.0000x reference)
//
#include <hip/hip_runtime.h>

#define TOKENS 2048
#define DM 1024
#define NHEAD 16
#define DH 64
#define SEQL 512
#define NBATCH 4
#define DFFN 4096
#define NLAYER 6
#define NVOCAB 32000

typedef short short8 __attribute__((ext_vector_type(8)));
typedef short short4v __attribute__((ext_vector_type(4)));
typedef float floatx4 __attribute__((ext_vector_type(4)));

#define FLAG_RELU 1
#define FLAG_OUTBF16 2

#define AS1 __attribute__((address_space(1)))
#define AS3 __attribute__((address_space(3)))

__device__ __forceinline__ float bf2f(short s) {
  unsigned u = ((unsigned)(unsigned short)s) << 16;
  return __builtin_bit_cast(float, u);
}
__device__ __forceinline__ short f2bf(float f) {
  unsigned u = __builtin_bit_cast(unsigned, f);
  u = (u + 0x7FFFu + ((u >> 16) & 1u)) >> 16;
  return (short)(unsigned short)u;
}

template<int N> __device__ __forceinline__ void wait_vm() {
  if constexpr (N == 0)      asm volatile("s_waitcnt vmcnt(0)" ::: "memory");
  else if constexpr (N == 3) asm volatile("s_waitcnt vmcnt(3)" ::: "memory");
  else if constexpr (N == 4) asm volatile("s_waitcnt vmcnt(4)" ::: "memory");
  else if constexpr (N == 6) asm volatile("s_waitcnt vmcnt(6)" ::: "memory");
  else if constexpr (N == 8) asm volatile("s_waitcnt vmcnt(8)" ::: "memory");
  else static_assert(N == 0, "unsupported vmcnt");
}

// ---------------------------------------------------------------------------
// gemm_db v5 (round-10 schedule; round-15 best configs, unchanged).
// Round-18: bias_k/bias_v params let the QKV epilogue select among the three
// per-layer bias vectors by ocol range (removes the bias_cat dispatch).
// Occupancy rules (r13/r15/r16): >=2 resident blocks/CU, grid <= residents*256
// even (fractional tail at lower residency costs ~15 us/layer).
// ---------------------------------------------------------------------------
template<int BM, int BN, int WR, int WC, int BK>
__global__ __launch_bounds__(256) void gemm_db(
    const short* __restrict__ A, const short* __restrict__ Bt, void* __restrict__ Cv,
    const float* __restrict__ bias, const float* __restrict__ biask,
    const float* __restrict__ biasv, const float* __restrict__ resid,
    int K, int lda, int ldb, int ldc, float alpha, int flags)
{
  constexpr int FI = BM / WR / 16;
  constexpr int FJ = BN / WC / 16;
  constexpr int RPI = (BK == 64) ? 32 : 64;
  constexpr int NST = BM / RPI + BN / RPI;
  __shared__ short As[2][BM * BK];
  __shared__ short Bs[2][BN * BK];

  const int gy = gridDim.y;
  int lin = blockIdx.x + gridDim.x * blockIdx.y;
  const int nwg = gridDim.x * gy;
  if ((nwg & 7) == 0) { const int cpx = nwg >> 3; lin = (lin & 7) * cpx + (lin >> 3); }
  const int row0 = (lin % gy) * BM, col0 = (lin / gy) * BN;

  const int tid = threadIdx.x;
  const int lane = tid & 63;
  const int wid = tid >> 6;
  const int wr = wid / WC, wc = wid % WC;
  const int lc = lane & 15, g = lane >> 4;
  const int sr = (BK == 64) ? (tid >> 3) : (tid >> 2);
  const int sc = (BK == 64) ? (tid & 7) : (tid & 3);
  const int swz_s = (BK == 64) ? (sr & 7) : ((sr >> 1) & 3);
  const int scs = (sc ^ swz_s) * 8;

  floatx4 acc[FI][FJ];
  #pragma unroll
  for (int i = 0; i < FI; ++i)
    #pragma unroll
    for (int j = 0; j < FJ; ++j)
      acc[i][j] = (floatx4){0.f, 0.f, 0.f, 0.f};

  auto stage = [&](int k0, int b) {
    char* ad = (char*)As[b];
    char* bd = (char*)Bs[b];
    #pragma unroll
    for (int it = 0; it < BM / RPI; ++it) {
      const short* src = A + (long)(row0 + it * RPI + sr) * lda + k0 + scs;
      __builtin_amdgcn_global_load_lds((const AS1 void*)src,
          (AS3 void*)(ad + it * 4096 + tid * 16), 16, 0, 0);
    }
    #pragma unroll
    for (int it = 0; it < BN / RPI; ++it) {
      const short* src = Bt + (long)(col0 + it * RPI + sr) * ldb + k0 + scs;
      __builtin_amdgcn_global_load_lds((const AS1 void*)src,
          (AS3 void*)(bd + it * 4096 + tid * 16), 16, 0, 0);
    }
  };

  const int NT = K / BK;
  stage(0, 0);
  int cb = 0;
  for (int t = 0; t < NT; ++t) {
    __builtin_amdgcn_s_barrier();
    __builtin_amdgcn_sched_barrier(0);
    if (t + 1 < NT) {
      stage((t + 1) * BK, cb ^ 1);
      wait_vm<NST>();
    } else {
      wait_vm<0>();
    }
    __builtin_amdgcn_sched_barrier(0);

    const short* as = As[cb];
    const short* bs = Bs[cb];
    if constexpr (BK == 64) {
      short8 fa[FI][2], fb[FJ][2];
      #pragma unroll
      for (int i = 0; i < FI; ++i) {
        const int r = wr * (BM / WR) + i * 16 + lc;
        fa[i][0] = *(const short8*)&as[r * 64 + ((g ^ (r & 7)) * 8)];
        fa[i][1] = *(const short8*)&as[r * 64 + (((4 + g) ^ (r & 7)) * 8)];
      }
      #pragma unroll
      for (int j = 0; j < FJ; ++j) {
        const int r = wc * (BN / WC) + j * 16 + lc;
        fb[j][0] = *(const short8*)&bs[r * 64 + ((g ^ (r & 7)) * 8)];
        fb[j][1] = *(const short8*)&bs[r * 64 + (((4 + g) ^ (r & 7)) * 8)];
      }
      #pragma unroll
      for (int i = 0; i < FI; ++i)
        #pragma unroll
        for (int j = 0; j < FJ; ++j) {
          acc[i][j] = __builtin_amdgcn_mfma_f32_16x16x32_bf16(fa[i][0], fb[j][0], acc[i][j], 0, 0, 0);
          acc[i][j] = __builtin_amdgcn_mfma_f32_16x16x32_bf16(fa[i][1], fb[j][1], acc[i][j], 0, 0, 0);
        }
    } else {
      short8 fa[FI], fb[FJ];
      #pragma unroll
      for (int i = 0; i < FI; ++i) {
        const int r = wr * (BM / WR) + i * 16 + lc;
        fa[i] = *(const short8*)&as[r * 32 + ((g ^ ((r >> 1) & 3)) * 8)];
      }
      #pragma unroll
      for (int j = 0; j < FJ; ++j) {
        const int r = wc * (BN / WC) + j * 16 + lc;
        fb[j] = *(const short8*)&bs[r * 32 + ((g ^ ((r >> 1) & 3)) * 8)];
      }
      #pragma unroll
      for (int i = 0; i < FI; ++i)
        #pragma unroll
        for (int j = 0; j < FJ; ++j)
          acc[i][j] = __builtin_amdgcn_mfma_f32_16x16x32_bf16(fa[i], fb[j], acc[i][j], 0, 0, 0);
    }
    cb ^= 1;
  }

  const bool relu = flags & FLAG_RELU;
  const bool obf  = flags & FLAG_OUTBF16;
  float* Cf = (float*)Cv;
  short* Cb = (short*)Cv;
  #pragma unroll
  for (int i = 0; i < FI; ++i) {
    int orow = row0 + wr * (BM / WR) + i * 16 + g * 4;
    #pragma unroll
    for (int j = 0; j < FJ; ++j) {
      int ocol = col0 + wc * (BN / WC) + j * 16 + lc;
      // QKV 3-way bias select (replaces bias_cat kernel)
      const float* bp = bias;
      int bc = ocol;
      if (biask) {
        if (ocol >= 2048)      { bp = biasv; bc = ocol - 2048; }
        else if (ocol >= 1024) { bp = biask; bc = ocol - 1024; }
      }
      #pragma unroll
      for (int t = 0; t < 4; ++t) {
        long off = (long)(orow + t) * ldc + ocol;
        float v = alpha * acc[i][j][t];
        if (bp)    v += bp[bc];
        if (resid) v += resid[off];
        if (relu)  v = fmaxf(v, 0.f);
        if (obf) Cb[off] = f2bf(v); else Cf[off] = v;
      }
    }
  }
}

template<int BM, int BN, int WR, int WC, int BK>
static inline void launch_gemm(hipStream_t st, const short* A, const short* Bt, void* C,
    const float* bias, const float* biask, const float* biasv, const float* resid,
    int M, int N, int K, int lda, int ldb, int ldc, float alpha, int flags)
{
  dim3 grid(N / BN, M / BM, 1), blk(256);
  gemm_db<BM, BN, WR, WC, BK><<<grid, blk, 0, st>>>(A, Bt, C, bias, biask, biasv, resid,
                                                    K, lda, ldb, ldc, alpha, flags);
}

// ---------------------------------------------------------------------------
// gemm256p: head-only 8-phase kernel (unchanged from round 12; ~191 us best).
// ---------------------------------------------------------------------------
__global__ __launch_bounds__(512, 2) void gemm256p(
    const short* __restrict__ A, const short* __restrict__ Bt, float* __restrict__ C,
    int K, int lda, int ldb, int ldc)
{
  __shared__ short As[2][2][128 * 64];
  __shared__ short Bs[2][4][64 * 64];

  const int gy = gridDim.y;
  int lin = blockIdx.x + gridDim.x * blockIdx.y;
  const int nwg = gridDim.x * gy;
  if ((nwg & 7) == 0) { const int cpx = nwg >> 3; lin = (lin & 7) * cpx + (lin >> 3); }
  const int row0 = (lin % gy) * 256, col0 = (lin / gy) * 256;

  const int tid = threadIdx.x;
  const int lane = tid & 63;
  const int w = tid >> 6;
  const int wr = w >> 2, wc = w & 3;
  const int lc = lane & 15, g = lane >> 4;
  const int sr = tid >> 3;
  const int sc = tid & 7;
  const int scs = (sc ^ (sr & 7)) * 8;

  floatx4 acc[8][4];
  #pragma unroll
  for (int i = 0; i < 8; ++i)
    #pragma unroll
    for (int j = 0; j < 4; ++j)
      acc[i][j] = (floatx4){0.f, 0.f, 0.f, 0.f};

  auto stageA = [&](int k0, int b, int h) {
    #pragma unroll
    for (int it = 0; it < 2; ++it) {
      const int r = h * 128 + it * 64 + sr;
      const short* src = A + (long)(row0 + r) * lda + k0 + scs;
      __builtin_amdgcn_global_load_lds((const AS1 void*)src,
          (AS3 void*)((char*)&As[b][h][0] + it * 8192 + tid * 16), 16, 0, 0);
    }
  };
  auto stageBq = [&](int k0, int b, int q) {
    const short* src = Bt + (long)(col0 + q * 64 + sr) * ldb + k0 + scs;
    __builtin_amdgcn_global_load_lds((const AS1 void*)src,
        (AS3 void*)((char*)&Bs[b][q][0] + tid * 16), 16, 0, 0);
  };
  auto rdA = [&](int b, int sub, short8 fa[4][2]) {
    const short* base = &As[b][wr][0];
    #pragma unroll
    for (int i = 0; i < 4; ++i) {
      const int r = sub * 64 + i * 16 + lc;
      fa[i][0] = *(const short8*)&base[r * 64 + ((g ^ (r & 7)) * 8)];
      fa[i][1] = *(const short8*)&base[r * 64 + (((4 + g) ^ (r & 7)) * 8)];
    }
  };
  auto rdB = [&](int b, int sub, short8 fb[2][2]) {
    const short* base = &Bs[b][wc][0];
    #pragma unroll
    for (int j = 0; j < 2; ++j) {
      const int r = sub * 32 + j * 16 + lc;
      fb[j][0] = *(const short8*)&base[r * 64 + ((g ^ (r & 7)) * 8)];
      fb[j][1] = *(const short8*)&base[r * 64 + (((4 + g) ^ (r & 7)) * 8)];
    }
  };
  auto mm = [&](short8 fa[4][2], short8 fb[2][2], int io, int jo) {
    #pragma unroll
    for (int i = 0; i < 4; ++i)
      #pragma unroll
      for (int j = 0; j < 2; ++j) {
        floatx4 c = acc[io + i][jo + j];
        c = __builtin_amdgcn_mfma_f32_16x16x32_bf16(fa[i][0], fb[j][0], c, 0, 0, 0);
        c = __builtin_amdgcn_mfma_f32_16x16x32_bf16(fa[i][1], fb[j][1], c, 0, 0, 0);
        acc[io + i][jo + j] = c;
      }
  };

#define PH_SYNC() \
    __builtin_amdgcn_s_barrier(); \
    asm volatile("s_waitcnt lgkmcnt(0)" ::: "memory"); \
    __builtin_amdgcn_sched_barrier(0); \
    __builtin_amdgcn_s_setprio(1);
#define PH_END() \
    __builtin_amdgcn_s_setprio(0); \
    __builtin_amdgcn_s_barrier();

  const int NT = K >> 6;
  stageA(0, 0, 0); stageA(0, 0, 1);
  stageBq(0, 0, 0); stageBq(0, 0, 1); stageBq(0, 0, 2); stageBq(0, 0, 3);
  stageA(64, 1, 0); stageA(64, 1, 1);
  wait_vm<4>();
  __builtin_amdgcn_s_barrier();

  for (int t = 0; t < NT; ++t) {
    const int b = t & 1;
    const int nk = (t + 1) << 6;
    short8 fa[4][2], fb0[2][2], fb1[2][2];
    rdA(b, 0, fa); rdB(b, 0, fb0);
    if (t + 1 < NT) { stageBq(nk, b ^ 1, 0); stageBq(nk, b ^ 1, 1); }
    PH_SYNC();
    mm(fa, fb0, 0, 0);
    PH_END();
    rdB(b, 1, fb1);
    if (t + 1 < NT) { stageBq(nk, b ^ 1, 2); stageBq(nk, b ^ 1, 3); }
    PH_SYNC();
    mm(fa, fb1, 0, 2);
    PH_END();
    rdA(b, 1, fa);
    PH_SYNC();
    mm(fa, fb1, 4, 2);
    PH_END();
    if (t + 2 < NT) {
      stageA((t + 2) << 6, b, 0); stageA((t + 2) << 6, b, 1);
      wait_vm<4>();
    } else {
      wait_vm<0>();
    }
    __builtin_amdgcn_sched_barrier(0);
    __builtin_amdgcn_s_barrier();
    __builtin_amdgcn_s_setprio(1);
    mm(fa, fb0, 4, 0);
    PH_END();
  }
#undef PH_SYNC
#undef PH_END

  #pragma unroll
  for (int i = 0; i < 8; ++i) {
    int orow = row0 + wr * 128 + i * 16 + g * 4;
    #pragma unroll
    for (int j = 0; j < 4; ++j) {
      int ocol = col0 + wc * 64 + j * 16 + lc;
      #pragma unroll
      for (int t = 0; t < 4; ++t)
        C[(long)(orow + t) * ldc + ocol] = acc[i][j][t];
    }
  }
}

// ---------------------------------------------------------------------------
// Flash attention + T13 defer-max (unchanged from round 14).
// ---------------------------------------------------------------------------
__global__ __launch_bounds__(256) void flash_attn(
    const short* __restrict__ qkv, const short* __restrict__ Vt,
    short* __restrict__ attn)
{
  const int qt = blockIdx.x;
  const int bh = blockIdx.y;
  const int b = bh >> 4, h = bh & 15;
  const int row0 = qt * 64;

  __shared__ short Kt[64 * 64];
  __shared__ short Vtl[64 * 64];
  __shared__ short Pt[4 * 16 * 64];

  const int tid = threadIdx.x;
  const int lane = tid & 63;
  const int wid = tid >> 6;
  const int lc = lane & 15, g = lane >> 4;

  short8 qf[2];
  {
    const short* qp = qkv + (long)(b * SEQL + row0 + wid * 16 + lc) * 3072 + h * DH;
    qf[0] = *(const short8*)(qp + g * 8);
    qf[1] = *(const short8*)(qp + 32 + g * 8);
  }

  floatx4 o[4];
  float m[4], l[4];
  #pragma unroll
  for (int j = 0; j < 4; ++j) o[j] = (floatx4){0.f, 0.f, 0.f, 0.f};
  #pragma unroll
  for (int t = 0; t < 4; ++t) { m[t] = -3e38f; l[t] = 0.f; }

  for (int kv0 = 0; kv0 <= row0; kv0 += 64) {
    #pragma unroll
    for (int i = 0; i < 2; ++i) {
      const int idx = i * 256 + tid;
      const int r = idx >> 3, cc = idx & 7;
      const int sw = cc ^ (r & 7);
      const short* ks = qkv + (long)(b * SEQL + kv0 + r) * 3072 + 1024 + h * DH + sw * 8;
      __builtin_amdgcn_global_load_lds((const AS1 void*)ks,
          (AS3 void*)((char*)Kt + (i * 256 + wid * 64) * 16), 16, 0, 0);
      const short* vs = Vt + (long)bh * DH * SEQL + (long)r * SEQL + kv0 + sw * 8;
      __builtin_amdgcn_global_load_lds((const AS1 void*)vs,
          (AS3 void*)((char*)Vtl + (i * 256 + wid * 64) * 16), 16, 0, 0);
    }
    __syncthreads();

    floatx4 s[4];
    #pragma unroll
    for (int j = 0; j < 4; ++j) s[j] = (floatx4){0.f, 0.f, 0.f, 0.f};
    #pragma unroll
    for (int ks_ = 0; ks_ < 2; ++ks_) {
      #pragma unroll
      for (int j = 0; j < 4; ++j) {
        const int row = j * 16 + lc;
        const short8 kf = *(const short8*)&Kt[row * 64 + ((ks_ * 4 + g) ^ (row & 7)) * 8];
        s[j] = __builtin_amdgcn_mfma_f32_16x16x32_bf16(qf[ks_], kf, s[j], 0, 0, 0);
      }
    }

    const bool diag = (kv0 == row0);
    float p[4][4], rmax[4], rsum[4];
    #pragma unroll
    for (int t = 0; t < 4; ++t) rmax[t] = -3e38f;
    #pragma unroll
    for (int j = 0; j < 4; ++j)
      #pragma unroll
      for (int t = 0; t < 4; ++t) {
        float sv = s[j][t] * 0.125f;
        if (diag && (j * 16 + lc) > (wid * 16 + g * 4 + t)) sv = -3e38f;
        p[j][t] = sv;
        rmax[t] = fmaxf(rmax[t], sv);
      }
    #pragma unroll
    for (int t = 0; t < 4; ++t) {
      #pragma unroll
      for (int mk = 1; mk < 16; mk <<= 1)
        rmax[t] = fmaxf(rmax[t], __shfl_xor(rmax[t], mk));
    }
    bool need = (rmax[0] > m[0] + 8.f) || (rmax[1] > m[1] + 8.f) ||
                (rmax[2] > m[2] + 8.f) || (rmax[3] > m[3] + 8.f);
    if (__any(need)) {
      float fs[4];
      #pragma unroll
      for (int t = 0; t < 4; ++t) {
        float mn = fmaxf(m[t], rmax[t]);
        fs[t] = __expf(m[t] - mn);
        m[t] = mn;
        l[t] *= fs[t];
      }
      #pragma unroll
      for (int j = 0; j < 4; ++j) {
        o[j][0] *= fs[0]; o[j][1] *= fs[1]; o[j][2] *= fs[2]; o[j][3] *= fs[3];
      }
    }
    #pragma unroll
    for (int j = 0; j < 4; ++j)
      #pragma unroll
      for (int t = 0; t < 4; ++t)
        p[j][t] = __expf(p[j][t] - m[t]);
    #pragma unroll
    for (int t = 0; t < 4; ++t) {
      rsum[t] = p[0][t] + p[1][t] + p[2][t] + p[3][t];
      #pragma unroll
      for (int mk = 1; mk < 16; mk <<= 1)
        rsum[t] += __shfl_xor(rsum[t], mk);
      l[t] += rsum[t];
    }
    #pragma unroll
    for (int j = 0; j < 4; ++j)
      #pragma unroll
      for (int t = 0; t < 4; ++t) {
        const int r = g * 4 + t;
        const int col = j * 16 + lc;
        Pt[wid * 1024 + r * 64 + (((col >> 3) ^ (r & 7)) * 8) + (col & 7)] = f2bf(p[j][t]);
      }
    __syncthreads();

    #pragma unroll
    for (int ks_ = 0; ks_ < 2; ++ks_) {
      const short8 pf = *(const short8*)&Pt[wid * 1024 + lc * 64 + ((ks_ * 4 + g) ^ (lc & 7)) * 8];
      #pragma unroll
      for (int j = 0; j < 4; ++j) {
        const int row = j * 16 + lc;
        const short8 vf = *(const short8*)&Vtl[row * 64 + ((ks_ * 4 + g) ^ (row & 7)) * 8];
        o[j] = __builtin_amdgcn_mfma_f32_16x16x32_bf16(pf, vf, o[j], 0, 0, 0);
      }
    }
    __syncthreads();
  }

  float linv[4];
  #pragma unroll
  for (int t = 0; t < 4; ++t) linv[t] = 1.f / l[t];
  #pragma unroll
  for (int j = 0; j < 4; ++j)
    #pragma unroll
    for (int t = 0; t < 4; ++t) {
      const long row = (long)(b * SEQL + row0 + wid * 16 + g * 4 + t);
      attn[row * DM + h * DH + j * 16 + lc] = f2bf(o[j][t] * linv[t]);
    }
}

// ---------------------------------------------------------------------------
__global__ __launch_bounds__(256) void ln_bf16(const float* __restrict__ x,
    const float* __restrict__ gg, const float* __restrict__ bb, short* __restrict__ out)
{
  int row = blockIdx.x;
  const float4 u = ((const float4*)(x + (long)row * DM))[threadIdx.x];
  float s  = u.x + u.y + u.z + u.w;
  float sq = u.x * u.x + u.y * u.y + u.z * u.z + u.w * u.w;
  #pragma unroll
  for (int o = 32; o; o >>= 1) { s += __shfl_xor(s, o); sq += __shfl_xor(sq, o); }
  __shared__ float red[8];
  int lane = threadIdx.x & 63, wid = threadIdx.x >> 6;
  if (lane == 0) { red[wid] = s; red[4 + wid] = sq; }
  __syncthreads();
  s  = red[0] + red[1] + red[2] + red[3];
  sq = red[4] + red[5] + red[6] + red[7];
  float mu  = s * (1.f / DM);
  float var = fmaxf(sq * (1.f / DM) - mu * mu, 0.f);
  float inv = 1.f / (sqrtf(var) + 1e-6f);
  int c = threadIdx.x * 4;
  const float4 gv = ((const float4*)gg)[threadIdx.x];
  const float4 bv = ((const float4*)bb)[threadIdx.x];
  short4v o;
  o[0] = f2bf((u.x - mu) * inv * gv.x + bv.x);
  o[1] = f2bf((u.y - mu) * inv * gv.y + bv.y);
  o[2] = f2bf((u.z - mu) * inv * gv.z + bv.z);
  o[3] = f2bf((u.w - mu) * inv * gv.w + bv.w);
  *(short4v*)(out + (long)row * DM + c) = o;
}

// ---------------------------------------------------------------------------
__global__ __launch_bounds__(256) void embed_k(const int* __restrict__ toks,
    const float* __restrict__ emb, const float* __restrict__ pos, float* __restrict__ x)
{
  int row = blockIdx.x;
  int s = row & (SEQL - 1);
  long tk = toks[row];
  const float4 e = ((const float4*)(emb + tk * DM))[threadIdx.x];
  const float4 p = ((const float4*)(pos + (long)s * DM))[threadIdx.x];
  float4 o;
  o.x = e.x * 32.f + p.x; o.y = e.y * 32.f + p.y;
  o.z = e.z * 32.f + p.z; o.w = e.w * 32.f + p.w;
  ((float4*)(x + (long)row * DM))[threadIdx.x] = o;
}

// ---------------------------------------------------------------------------
// wtrans4: merged transpose+convert of the four [L][1024][1024] weights into
// bf16 [N][K] panels (replaces 4 separate wtrans dispatches).
// z = w*NLAYER + l; w in {0:Wq,1:Wk,2:Wv -> Wqkvt col-block w; 3:Wo -> Wot}.
// ---------------------------------------------------------------------------
__global__ void wtrans4(const float* __restrict__ Wq, const float* __restrict__ Wk,
                        const float* __restrict__ Wv, const float* __restrict__ Wo,
                        short* __restrict__ Wqkvt, short* __restrict__ Wot)
{
  __shared__ float tile[32][33];
  const int z = blockIdx.z;
  const int w = z / NLAYER, l = z % NLAYER;
  const float* W = (w == 0) ? Wq : (w == 1) ? Wk : (w == 2) ? Wv : Wo;
  const long lo = (long)l * DM * DM;
  short* dst;
  long oo;
  if (w < 3) { dst = Wqkvt; oo = (long)l * 3072 * DM + (long)w * DM * DM; }
  else       { dst = Wot;   oo = (long)l * DM * DM; }
  int n0 = blockIdx.x * 32, k0 = blockIdx.y * 32;
  int tx = threadIdx.x, ty = threadIdx.y;
  #pragma unroll
  for (int i = 0; i < 4; ++i)
    tile[ty + i * 8][tx] = W[lo + (long)(k0 + ty + i * 8) * DM + n0 + tx];
  __syncthreads();
  #pragma unroll
  for (int i = 0; i < 4; ++i)
    dst[oo + (long)(n0 + ty + i * 8) * DM + k0 + tx] = f2bf(tile[tx][ty + i * 8]);
}

// ---------------------------------------------------------------------------
// wtransF: merged transpose+convert for W1 [L][DM][DFFN] and W2 [L][DFFN][DM]
// (replaces 2 wtrans dispatches). z = w*NLAYER + l.
// w=0: K=DM,N=DFFN, n0 from x (128 blks), k0 from y (32 blks)
// w=1: K=DFFN,N=DM, n0 from y (32 blks),  k0 from x (128 blks)
// ---------------------------------------------------------------------------
__global__ void wtransF(const float* __restrict__ W1, const float* __restrict__ W2,
                        short* __restrict__ W1t, short* __restrict__ W2t)
{
  __shared__ float tile[32][33];
  const int z = blockIdx.z;
  const int w = z / NLAYER, l = z % NLAYER;
  const int K = w ? DFFN : DM;
  const int N = w ? DM : DFFN;
  const float* W = w ? W2 : W1;
  short* dst = (w ? W2t : W1t);
  const long lo = (long)l * DM * DFFN;
  const long oo = (long)l * DM * DFFN;
  int n0 = (w ? blockIdx.y : blockIdx.x) * 32;
  int k0 = (w ? blockIdx.x : blockIdx.y) * 32;
  int tx = threadIdx.x, ty = threadIdx.y;
  #pragma unroll
  for (int i = 0; i < 4; ++i)
    tile[ty + i * 8][tx] = W[lo + (long)(k0 + ty + i * 8) * N + n0 + tx];
  __syncthreads();
  #pragma unroll
  for (int i = 0; i < 4; ++i)
    dst[oo + (long)(n0 + ty + i * 8) * K + k0 + tx] = f2bf(tile[tx][ty + i * 8]);
}

// ---------------------------------------------------------------------------
__global__ __launch_bounds__(256) void conv_bf16(const float* __restrict__ in,
                                                 short* __restrict__ out)
{
  long i = ((long)blockIdx.x * 256 + threadIdx.x) * 8;
  float4 a = *(const float4*)(in + i);
  float4 b = *(const float4*)(in + i + 4);
  short8 o;
  o[0] = f2bf(a.x); o[1] = f2bf(a.y); o[2] = f2bf(a.z); o[3] = f2bf(a.w);
  o[4] = f2bf(b.x); o[5] = f2bf(b.y); o[6] = f2bf(b.z); o[7] = f2bf(b.w);
  *(short8*)(out + i) = o;
}

// ---------------------------------------------------------------------------
__global__ void vtrans(const short* __restrict__ qkv, short* __restrict__ Vt)
{
  __shared__ short tile[32][33];
  int bh = blockIdx.z;
  int b = bh >> 4, h = bh & 15;
  int s0 = blockIdx.x * 32, d0 = blockIdx.y * 32;
  int tx = threadIdx.x, ty = threadIdx.y;
  #pragma unroll
  for (int i = 0; i < 4; ++i)
    tile[ty + i * 8][tx] =
        qkv[((long)(b * SEQL + s0 + ty + i * 8)) * 3072 + 2048 + h * DH + d0 + tx];
  __syncthreads();
  #pragma unroll
  for (int i = 0; i < 4; ++i)
    Vt[((long)(bh * DH + d0 + ty + i * 8)) * SEQL + s0 + tx] = tile[tx][ty + i * 8];
}

// ---------------------------------------------------------------------------
extern "C" void kernel_launch(void* const* d_in, const int* in_sizes, int n_in,
                              void* d_out, int out_size, void* d_ws, size_t ws_size,
                              hipStream_t stream)
{
  (void)in_sizes; (void)n_in; (void)out_size;
  const int*   toks = (const int*)  d_in[0];
  const float* temb = (const float*)d_in[1];
  const float* pemb = (const float*)d_in[2];
  const float* Wq  = (const float*)d_in[3];  const float* bq  = (const float*)d_in[4];
  const float* Wk  = (const float*)d_in[5];  const float* bk  = (const float*)d_in[6];
  const float* Wv  = (const float*)d_in[7];  const float* bv  = (const float*)d_in[8];
  const float* Wo  = (const float*)d_in[9];  const float* bo  = (const float*)d_in[10];
  const float* g1  = (const float*)d_in[11]; const float* be1 = (const float*)d_in[12];
  const float* W1  = (const float*)d_in[13]; const float* bf1 = (const float*)d_in[14];
  const float* W2  = (const float*)d_in[15]; const float* bf2 = (const float*)d_in[16];
  const float* g2  = (const float*)d_in[17]; const float* be2 = (const float*)d_in[18];
  const float* gf  = (const float*)d_in[19]; const float* bfb = (const float*)d_in[20];

  char* p = (char*)d_ws;
  auto carve = [&](size_t bytes) -> char* {
    char* r = p;
    p += (bytes + 255) & ~(size_t)255;
    return r;
  };
  short* h     = (short*)carve((size_t)TOKENS * DM * 2);
  char*  uni   = p;
  short* tembb = (short*)uni;  // bf16 tok_emb overlaps dead weight region at the end
  short* Wqkvt = (short*)carve((size_t)NLAYER * 3072 * DM * 2);
  short* Wot   = (short*)carve((size_t)NLAYER * DM * DM * 2);
  short* W1t   = (short*)carve((size_t)NLAYER * DM * DFFN * 2);
  short* W2t   = (short*)carve((size_t)NLAYER * DM * DFFN * 2);
  float* x     = (float*)carve((size_t)TOKENS * DM * 4);
  short* qkv   = (short*)carve((size_t)TOKENS * 3072 * 2);
  short* attn  = (short*)carve((size_t)TOKENS * DM * 2);
  short* Vt    = (short*)carve((size_t)NBATCH * NHEAD * DH * SEQL * 2);
  short* ffb   = (short*)carve((size_t)TOKENS * DFFN * 2);
  size_t used = (size_t)(p - (char*)d_ws);
  size_t need_t = (size_t)(uni - (char*)d_ws) + (size_t)NVOCAB * DM * 2;
  if (used > ws_size || need_t > ws_size) return;

  dim3 tb(32, 8);

  embed_k<<<TOKENS, 256, 0, stream>>>(toks, temb, pemb, x);
  // merged weight transposes: 2 dispatches instead of 6
  wtrans4<<<dim3(DM / 32, DM / 32, 4 * NLAYER), tb, 0, stream>>>(Wq, Wk, Wv, Wo, Wqkvt, Wot);
  wtransF<<<dim3(DFFN / 32, DM / 32, 2 * NLAYER), tb, 0, stream>>>(W1, W2, W1t, W2t);

  for (int l = 0; l < NLAYER; ++l) {
    const size_t wqkv = (size_t)l * 3072 * DM;
    const size_t wdd  = (size_t)l * DM * DM;
    const size_t wdf  = (size_t)l * DM * DFFN;
    ln_bf16<<<TOKENS, 256, 0, stream>>>(x, g1 + l * DM, be1 + l * DM, h);
    // QKV: 3-way bias select in epilogue (bias_cat kernel removed)
    launch_gemm<64, 128, 1, 4, 64>(stream, h, Wqkvt + wqkv, qkv,
        bq + l * DM, bk + l * DM, bv + l * DM, nullptr,
        TOKENS, 3072, DM, DM, DM, 3072, 1.f, FLAG_OUTBF16);
    vtrans<<<dim3(SEQL / 32, DH / 32, NBATCH * NHEAD), tb, 0, stream>>>(qkv, Vt);
    flash_attn<<<dim3(SEQL / 64, NBATCH * NHEAD), 256, 0, stream>>>(qkv, Vt, attn);
    launch_gemm<64, 64, 2, 2, 64>(stream, attn, Wot + wdd, x,
        bo + l * DM, nullptr, nullptr, x,
        TOKENS, DM, DM, DM, DM, DM, 1.f, 0);
    ln_bf16<<<TOKENS, 256, 0, stream>>>(x, g2 + l * DM, be2 + l * DM, h);
    launch_gemm<128, 128, 2, 2, 64>(stream, h, W1t + wdf, ffb,
        bf1 + l * DFFN, nullptr, nullptr, nullptr,
        TOKENS, DFFN, DM, DM, DM, DFFN, 1.f, FLAG_OUTBF16 | FLAG_RELU);
    launch_gemm<64, 64, 2, 2, 64>(stream, ffb, W2t + wdf, x,
        bf2 + l * DM, nullptr, nullptr, x,
        TOKENS, DM, DFFN, DFFN, DFFN, DM, 1.f, 0);
  }
  ln_bf16<<<TOKENS, 256, 0, stream>>>(x, gf, bfb, h);
  conv_bf16<<<(NVOCAB * DM) / (256 * 8), 256, 0, stream>>>(temb, tembb);
  {
    dim3 grid(NVOCAB / 256, TOKENS / 256, 1), blk(512);
    gemm256p<<<grid, blk, 0, stream>>>(h, tembb, (float*)d_out, DM, DM, DM, NVOCAB);
  }
}

// Round 19
// 1329.316 us; speedup vs baseline: 1.0213x; 1.0213x over previous
//
#include <hip/hip_runtime.h>

#define TOKENS 2048
#define DM 1024
#define NHEAD 16
#define DH 64
#define SEQL 512
#define NBATCH 4
#define DFFN 4096
#define NLAYER 6
#define NVOCAB 32000

typedef short short8 __attribute__((ext_vector_type(8)));
typedef short short4v __attribute__((ext_vector_type(4)));
typedef float floatx4 __attribute__((ext_vector_type(4)));

#define FLAG_RELU 1
#define FLAG_OUTBF16 2
#define FLAG_VTL 4

#define AS1 __attribute__((address_space(1)))
#define AS3 __attribute__((address_space(3)))

__device__ __forceinline__ float bf2f(short s) {
  unsigned u = ((unsigned)(unsigned short)s) << 16;
  return __builtin_bit_cast(float, u);
}
__device__ __forceinline__ short f2bf(float f) {
  unsigned u = __builtin_bit_cast(unsigned, f);
  u = (u + 0x7FFFu + ((u >> 16) & 1u)) >> 16;
  return (short)(unsigned short)u;
}

template<int N> __device__ __forceinline__ void wait_vm() {
  if constexpr (N == 0)      asm volatile("s_waitcnt vmcnt(0)" ::: "memory");
  else if constexpr (N == 3) asm volatile("s_waitcnt vmcnt(3)" ::: "memory");
  else if constexpr (N == 4) asm volatile("s_waitcnt vmcnt(4)" ::: "memory");
  else if constexpr (N == 6) asm volatile("s_waitcnt vmcnt(6)" ::: "memory");
  else if constexpr (N == 8) asm volatile("s_waitcnt vmcnt(8)" ::: "memory");
  else static_assert(N == 0, "unsupported vmcnt");
}

// ---------------------------------------------------------------------------
// gemm_db v5 (round-10 schedule; round-15 best tile configs).
// Round-19: FLAG_VTL — QKV blocks with col0>=2048 (V columns) write their
// output TRANSPOSED into Vt[B*H][DH][SEQL] via an LDS round-trip (NOT the r9
// per-lane scatter): acc -> LDS tile [128c][72] (short4, 16B-aligned rows) ->
// 64B-contiguous global runs. Removes the per-layer vtrans dispatch. V cols
// are no longer written to qkv (flash never reads them).
// Occupancy rules (r13/r15/r16): >=2 resident blocks/CU, grid even multiple.
// ---------------------------------------------------------------------------
template<int BM, int BN, int WR, int WC, int BK>
__global__ __launch_bounds__(256) void gemm_db(
    const short* __restrict__ A, const short* __restrict__ Bt, void* __restrict__ Cv,
    const float* __restrict__ bias, const float* __restrict__ biask,
    const float* __restrict__ biasv, const float* __restrict__ resid,
    short* __restrict__ vt,
    int K, int lda, int ldb, int ldc, float alpha, int flags)
{
  constexpr int FI = BM / WR / 16;
  constexpr int FJ = BN / WC / 16;
  constexpr int RPI = (BK == 64) ? 32 : 64;
  constexpr int NST = BM / RPI + BN / RPI;
  __shared__ short As[2][BM * BK];
  __shared__ short Bs[2][BN * BK];

  const int gy = gridDim.y;
  int lin = blockIdx.x + gridDim.x * blockIdx.y;
  const int nwg = gridDim.x * gy;
  if ((nwg & 7) == 0) { const int cpx = nwg >> 3; lin = (lin & 7) * cpx + (lin >> 3); }
  const int row0 = (lin % gy) * BM, col0 = (lin / gy) * BN;

  const int tid = threadIdx.x;
  const int lane = tid & 63;
  const int wid = tid >> 6;
  const int wr = wid / WC, wc = wid % WC;
  const int lc = lane & 15, g = lane >> 4;
  const int sr = (BK == 64) ? (tid >> 3) : (tid >> 2);
  const int sc = (BK == 64) ? (tid & 7) : (tid & 3);
  const int swz_s = (BK == 64) ? (sr & 7) : ((sr >> 1) & 3);
  const int scs = (sc ^ swz_s) * 8;

  floatx4 acc[FI][FJ];
  #pragma unroll
  for (int i = 0; i < FI; ++i)
    #pragma unroll
    for (int j = 0; j < FJ; ++j)
      acc[i][j] = (floatx4){0.f, 0.f, 0.f, 0.f};

  auto stage = [&](int k0, int b) {
    char* ad = (char*)As[b];
    char* bd = (char*)Bs[b];
    #pragma unroll
    for (int it = 0; it < BM / RPI; ++it) {
      const short* src = A + (long)(row0 + it * RPI + sr) * lda + k0 + scs;
      __builtin_amdgcn_global_load_lds((const AS1 void*)src,
          (AS3 void*)(ad + it * 4096 + tid * 16), 16, 0, 0);
    }
    #pragma unroll
    for (int it = 0; it < BN / RPI; ++it) {
      const short* src = Bt + (long)(col0 + it * RPI + sr) * ldb + k0 + scs;
      __builtin_amdgcn_global_load_lds((const AS1 void*)src,
          (AS3 void*)(bd + it * 4096 + tid * 16), 16, 0, 0);
    }
  };

  const int NT = K / BK;
  stage(0, 0);
  int cb = 0;
  for (int t = 0; t < NT; ++t) {
    __builtin_amdgcn_s_barrier();
    __builtin_amdgcn_sched_barrier(0);
    if (t + 1 < NT) {
      stage((t + 1) * BK, cb ^ 1);
      wait_vm<NST>();
    } else {
      wait_vm<0>();
    }
    __builtin_amdgcn_sched_barrier(0);

    const short* as = As[cb];
    const short* bs = Bs[cb];
    if constexpr (BK == 64) {
      short8 fa[FI][2], fb[FJ][2];
      #pragma unroll
      for (int i = 0; i < FI; ++i) {
        const int r = wr * (BM / WR) + i * 16 + lc;
        fa[i][0] = *(const short8*)&as[r * 64 + ((g ^ (r & 7)) * 8)];
        fa[i][1] = *(const short8*)&as[r * 64 + (((4 + g) ^ (r & 7)) * 8)];
      }
      #pragma unroll
      for (int j = 0; j < FJ; ++j) {
        const int r = wc * (BN / WC) + j * 16 + lc;
        fb[j][0] = *(const short8*)&bs[r * 64 + ((g ^ (r & 7)) * 8)];
        fb[j][1] = *(const short8*)&bs[r * 64 + (((4 + g) ^ (r & 7)) * 8)];
      }
      #pragma unroll
      for (int i = 0; i < FI; ++i)
        #pragma unroll
        for (int j = 0; j < FJ; ++j) {
          acc[i][j] = __builtin_amdgcn_mfma_f32_16x16x32_bf16(fa[i][0], fb[j][0], acc[i][j], 0, 0, 0);
          acc[i][j] = __builtin_amdgcn_mfma_f32_16x16x32_bf16(fa[i][1], fb[j][1], acc[i][j], 0, 0, 0);
        }
    } else {
      short8 fa[FI], fb[FJ];
      #pragma unroll
      for (int i = 0; i < FI; ++i) {
        const int r = wr * (BM / WR) + i * 16 + lc;
        fa[i] = *(const short8*)&as[r * 32 + ((g ^ ((r >> 1) & 3)) * 8)];
      }
      #pragma unroll
      for (int j = 0; j < FJ; ++j) {
        const int r = wc * (BN / WC) + j * 16 + lc;
        fb[j] = *(const short8*)&bs[r * 32 + ((g ^ ((r >> 1) & 3)) * 8)];
      }
      #pragma unroll
      for (int i = 0; i < FI; ++i)
        #pragma unroll
        for (int j = 0; j < FJ; ++j)
          acc[i][j] = __builtin_amdgcn_mfma_f32_16x16x32_bf16(fa[i], fb[j], acc[i][j], 0, 0, 0);
    }
    cb ^= 1;
  }

  // ---- fused V-transpose epilogue (block-uniform branch) ----
  if ((flags & FLAG_VTL) && col0 >= 2048) {
    __syncthreads();                       // all waves done reading As/Bs
    short* T = (short*)&Bs[0][0];          // [128 c][72] shorts = 18 KB
    #pragma unroll
    for (int i = 0; i < FI; ++i) {
      const int rowl = wr * (BM / WR) + i * 16 + g * 4;   // token-local (t=0)
      #pragma unroll
      for (int j = 0; j < FJ; ++j) {
        const int c  = wc * (BN / WC) + j * 16 + lc;      // V col-local 0..127
        const int bc = col0 + c - 2048;                   // bias index
        short4v o4;
        #pragma unroll
        for (int t = 0; t < 4; ++t)
          o4[t] = f2bf(alpha * acc[i][j][t] + biasv[bc]);
        *(short4v*)&T[c * 72 + rowl] = o4;                // 8B aligned
      }
    }
    __syncthreads();
    const int c = tid & 127, half = tid >> 7;
    const int vcol = col0 - 2048 + c;
    const long dstrow = ((long)(row0 >> 9) * NHEAD + (vcol >> 6)) * DH + (vcol & 63);
    short* dst = vt + dstrow * SEQL + (row0 & (SEQL - 1)) + half * 32;
    const short* src = &T[c * 72 + half * 32];
    #pragma unroll
    for (int k2 = 0; k2 < 4; ++k2)
      *(short8*)(dst + k2 * 8) = *(const short8*)(src + k2 * 8);
    return;
  }

  const bool relu = flags & FLAG_RELU;
  const bool obf  = flags & FLAG_OUTBF16;
  float* Cf = (float*)Cv;
  short* Cb = (short*)Cv;
  #pragma unroll
  for (int i = 0; i < FI; ++i) {
    int orow = row0 + wr * (BM / WR) + i * 16 + g * 4;
    #pragma unroll
    for (int j = 0; j < FJ; ++j) {
      int ocol = col0 + wc * (BN / WC) + j * 16 + lc;
      // QKV 2-way bias select (q/k; v handled by the VTL path)
      const float* bp = bias;
      int bc = ocol;
      if (biask && ocol >= 1024) { bp = biask; bc = ocol - 1024; }
      #pragma unroll
      for (int t = 0; t < 4; ++t) {
        long off = (long)(orow + t) * ldc + ocol;
        float v = alpha * acc[i][j][t];
        if (bp)    v += bp[bc];
        if (resid) v += resid[off];
        if (relu)  v = fmaxf(v, 0.f);
        if (obf) Cb[off] = f2bf(v); else Cf[off] = v;
      }
    }
  }
}

template<int BM, int BN, int WR, int WC, int BK>
static inline void launch_gemm(hipStream_t st, const short* A, const short* Bt, void* C,
    const float* bias, const float* biask, const float* biasv, const float* resid,
    short* vt, int M, int N, int K, int lda, int ldb, int ldc, float alpha, int flags)
{
  dim3 grid(N / BN, M / BM, 1), blk(256);
  gemm_db<BM, BN, WR, WC, BK><<<grid, blk, 0, st>>>(A, Bt, C, bias, biask, biasv, resid,
                                                    vt, K, lda, ldb, ldc, alpha, flags);
}

// ---------------------------------------------------------------------------
// gemm256p: head-only 8-phase kernel (unchanged; ~191 us best).
// ---------------------------------------------------------------------------
__global__ __launch_bounds__(512, 2) void gemm256p(
    const short* __restrict__ A, const short* __restrict__ Bt, float* __restrict__ C,
    int K, int lda, int ldb, int ldc)
{
  __shared__ short As[2][2][128 * 64];
  __shared__ short Bs[2][4][64 * 64];

  const int gy = gridDim.y;
  int lin = blockIdx.x + gridDim.x * blockIdx.y;
  const int nwg = gridDim.x * gy;
  if ((nwg & 7) == 0) { const int cpx = nwg >> 3; lin = (lin & 7) * cpx + (lin >> 3); }
  const int row0 = (lin % gy) * 256, col0 = (lin / gy) * 256;

  const int tid = threadIdx.x;
  const int lane = tid & 63;
  const int w = tid >> 6;
  const int wr = w >> 2, wc = w & 3;
  const int lc = lane & 15, g = lane >> 4;
  const int sr = tid >> 3;
  const int sc = tid & 7;
  const int scs = (sc ^ (sr & 7)) * 8;

  floatx4 acc[8][4];
  #pragma unroll
  for (int i = 0; i < 8; ++i)
    #pragma unroll
    for (int j = 0; j < 4; ++j)
      acc[i][j] = (floatx4){0.f, 0.f, 0.f, 0.f};

  auto stageA = [&](int k0, int b, int h) {
    #pragma unroll
    for (int it = 0; it < 2; ++it) {
      const int r = h * 128 + it * 64 + sr;
      const short* src = A + (long)(row0 + r) * lda + k0 + scs;
      __builtin_amdgcn_global_load_lds((const AS1 void*)src,
          (AS3 void*)((char*)&As[b][h][0] + it * 8192 + tid * 16), 16, 0, 0);
    }
  };
  auto stageBq = [&](int k0, int b, int q) {
    const short* src = Bt + (long)(col0 + q * 64 + sr) * ldb + k0 + scs;
    __builtin_amdgcn_global_load_lds((const AS1 void*)src,
        (AS3 void*)((char*)&Bs[b][q][0] + tid * 16), 16, 0, 0);
  };
  auto rdA = [&](int b, int sub, short8 fa[4][2]) {
    const short* base = &As[b][wr][0];
    #pragma unroll
    for (int i = 0; i < 4; ++i) {
      const int r = sub * 64 + i * 16 + lc;
      fa[i][0] = *(const short8*)&base[r * 64 + ((g ^ (r & 7)) * 8)];
      fa[i][1] = *(const short8*)&base[r * 64 + (((4 + g) ^ (r & 7)) * 8)];
    }
  };
  auto rdB = [&](int b, int sub, short8 fb[2][2]) {
    const short* base = &Bs[b][wc][0];
    #pragma unroll
    for (int j = 0; j < 2; ++j) {
      const int r = sub * 32 + j * 16 + lc;
      fb[j][0] = *(const short8*)&base[r * 64 + ((g ^ (r & 7)) * 8)];
      fb[j][1] = *(const short8*)&base[r * 64 + (((4 + g) ^ (r & 7)) * 8)];
    }
  };
  auto mm = [&](short8 fa[4][2], short8 fb[2][2], int io, int jo) {
    #pragma unroll
    for (int i = 0; i < 4; ++i)
      #pragma unroll
      for (int j = 0; j < 2; ++j) {
        floatx4 c = acc[io + i][jo + j];
        c = __builtin_amdgcn_mfma_f32_16x16x32_bf16(fa[i][0], fb[j][0], c, 0, 0, 0);
        c = __builtin_amdgcn_mfma_f32_16x16x32_bf16(fa[i][1], fb[j][1], c, 0, 0, 0);
        acc[io + i][jo + j] = c;
      }
  };

#define PH_SYNC() \
    __builtin_amdgcn_s_barrier(); \
    asm volatile("s_waitcnt lgkmcnt(0)" ::: "memory"); \
    __builtin_amdgcn_sched_barrier(0); \
    __builtin_amdgcn_s_setprio(1);
#define PH_END() \
    __builtin_amdgcn_s_setprio(0); \
    __builtin_amdgcn_s_barrier();

  const int NT = K >> 6;
  stageA(0, 0, 0); stageA(0, 0, 1);
  stageBq(0, 0, 0); stageBq(0, 0, 1); stageBq(0, 0, 2); stageBq(0, 0, 3);
  stageA(64, 1, 0); stageA(64, 1, 1);
  wait_vm<4>();
  __builtin_amdgcn_s_barrier();

  for (int t = 0; t < NT; ++t) {
    const int b = t & 1;
    const int nk = (t + 1) << 6;
    short8 fa[4][2], fb0[2][2], fb1[2][2];
    rdA(b, 0, fa); rdB(b, 0, fb0);
    if (t + 1 < NT) { stageBq(nk, b ^ 1, 0); stageBq(nk, b ^ 1, 1); }
    PH_SYNC();
    mm(fa, fb0, 0, 0);
    PH_END();
    rdB(b, 1, fb1);
    if (t + 1 < NT) { stageBq(nk, b ^ 1, 2); stageBq(nk, b ^ 1, 3); }
    PH_SYNC();
    mm(fa, fb1, 0, 2);
    PH_END();
    rdA(b, 1, fa);
    PH_SYNC();
    mm(fa, fb1, 4, 2);
    PH_END();
    if (t + 2 < NT) {
      stageA((t + 2) << 6, b, 0); stageA((t + 2) << 6, b, 1);
      wait_vm<4>();
    } else {
      wait_vm<0>();
    }
    __builtin_amdgcn_sched_barrier(0);
    __builtin_amdgcn_s_barrier();
    __builtin_amdgcn_s_setprio(1);
    mm(fa, fb0, 4, 0);
    PH_END();
  }
#undef PH_SYNC
#undef PH_END

  #pragma unroll
  for (int i = 0; i < 8; ++i) {
    int orow = row0 + wr * 128 + i * 16 + g * 4;
    #pragma unroll
    for (int j = 0; j < 4; ++j) {
      int ocol = col0 + wc * 64 + j * 16 + lc;
      #pragma unroll
      for (int t = 0; t < 4; ++t)
        C[(long)(orow + t) * ldc + ocol] = acc[i][j][t];
    }
  }
}

// ---------------------------------------------------------------------------
// Flash attention + T13 defer-max (unchanged from round 14).
// ---------------------------------------------------------------------------
__global__ __launch_bounds__(256) void flash_attn(
    const short* __restrict__ qkv, const short* __restrict__ Vt,
    short* __restrict__ attn)
{
  const int qt = blockIdx.x;
  const int bh = blockIdx.y;
  const int b = bh >> 4, h = bh & 15;
  const int row0 = qt * 64;

  __shared__ short Kt[64 * 64];
  __shared__ short Vtl[64 * 64];
  __shared__ short Pt[4 * 16 * 64];

  const int tid = threadIdx.x;
  const int lane = tid & 63;
  const int wid = tid >> 6;
  const int lc = lane & 15, g = lane >> 4;

  short8 qf[2];
  {
    const short* qp = qkv + (long)(b * SEQL + row0 + wid * 16 + lc) * 3072 + h * DH;
    qf[0] = *(const short8*)(qp + g * 8);
    qf[1] = *(const short8*)(qp + 32 + g * 8);
  }

  floatx4 o[4];
  float m[4], l[4];
  #pragma unroll
  for (int j = 0; j < 4; ++j) o[j] = (floatx4){0.f, 0.f, 0.f, 0.f};
  #pragma unroll
  for (int t = 0; t < 4; ++t) { m[t] = -3e38f; l[t] = 0.f; }

  for (int kv0 = 0; kv0 <= row0; kv0 += 64) {
    #pragma unroll
    for (int i = 0; i < 2; ++i) {
      const int idx = i * 256 + tid;
      const int r = idx >> 3, cc = idx & 7;
      const int sw = cc ^ (r & 7);
      const short* ks = qkv + (long)(b * SEQL + kv0 + r) * 3072 + 1024 + h * DH + sw * 8;
      __builtin_amdgcn_global_load_lds((const AS1 void*)ks,
          (AS3 void*)((char*)Kt + (i * 256 + wid * 64) * 16), 16, 0, 0);
      const short* vs = Vt + (long)bh * DH * SEQL + (long)r * SEQL + kv0 + sw * 8;
      __builtin_amdgcn_global_load_lds((const AS1 void*)vs,
          (AS3 void*)((char*)Vtl + (i * 256 + wid * 64) * 16), 16, 0, 0);
    }
    __syncthreads();

    floatx4 s[4];
    #pragma unroll
    for (int j = 0; j < 4; ++j) s[j] = (floatx4){0.f, 0.f, 0.f, 0.f};
    #pragma unroll
    for (int ks_ = 0; ks_ < 2; ++ks_) {
      #pragma unroll
      for (int j = 0; j < 4; ++j) {
        const int row = j * 16 + lc;
        const short8 kf = *(const short8*)&Kt[row * 64 + ((ks_ * 4 + g) ^ (row & 7)) * 8];
        s[j] = __builtin_amdgcn_mfma_f32_16x16x32_bf16(qf[ks_], kf, s[j], 0, 0, 0);
      }
    }

    const bool diag = (kv0 == row0);
    float p[4][4], rmax[4], rsum[4];
    #pragma unroll
    for (int t = 0; t < 4; ++t) rmax[t] = -3e38f;
    #pragma unroll
    for (int j = 0; j < 4; ++j)
      #pragma unroll
      for (int t = 0; t < 4; ++t) {
        float sv = s[j][t] * 0.125f;
        if (diag && (j * 16 + lc) > (wid * 16 + g * 4 + t)) sv = -3e38f;
        p[j][t] = sv;
        rmax[t] = fmaxf(rmax[t], sv);
      }
    #pragma unroll
    for (int t = 0; t < 4; ++t) {
      #pragma unroll
      for (int mk = 1; mk < 16; mk <<= 1)
        rmax[t] = fmaxf(rmax[t], __shfl_xor(rmax[t], mk));
    }
    bool need = (rmax[0] > m[0] + 8.f) || (rmax[1] > m[1] + 8.f) ||
                (rmax[2] > m[2] + 8.f) || (rmax[3] > m[3] + 8.f);
    if (__any(need)) {
      float fs[4];
      #pragma unroll
      for (int t = 0; t < 4; ++t) {
        float mn = fmaxf(m[t], rmax[t]);
        fs[t] = __expf(m[t] - mn);
        m[t] = mn;
        l[t] *= fs[t];
      }
      #pragma unroll
      for (int j = 0; j < 4; ++j) {
        o[j][0] *= fs[0]; o[j][1] *= fs[1]; o[j][2] *= fs[2]; o[j][3] *= fs[3];
      }
    }
    #pragma unroll
    for (int j = 0; j < 4; ++j)
      #pragma unroll
      for (int t = 0; t < 4; ++t)
        p[j][t] = __expf(p[j][t] - m[t]);
    #pragma unroll
    for (int t = 0; t < 4; ++t) {
      rsum[t] = p[0][t] + p[1][t] + p[2][t] + p[3][t];
      #pragma unroll
      for (int mk = 1; mk < 16; mk <<= 1)
        rsum[t] += __shfl_xor(rsum[t], mk);
      l[t] += rsum[t];
    }
    #pragma unroll
    for (int j = 0; j < 4; ++j)
      #pragma unroll
      for (int t = 0; t < 4; ++t) {
        const int r = g * 4 + t;
        const int col = j * 16 + lc;
        Pt[wid * 1024 + r * 64 + (((col >> 3) ^ (r & 7)) * 8) + (col & 7)] = f2bf(p[j][t]);
      }
    __syncthreads();

    #pragma unroll
    for (int ks_ = 0; ks_ < 2; ++ks_) {
      const short8 pf = *(const short8*)&Pt[wid * 1024 + lc * 64 + ((ks_ * 4 + g) ^ (lc & 7)) * 8];
      #pragma unroll
      for (int j = 0; j < 4; ++j) {
        const int row = j * 16 + lc;
        const short8 vf = *(const short8*)&Vtl[row * 64 + ((ks_ * 4 + g) ^ (row & 7)) * 8];
        o[j] = __builtin_amdgcn_mfma_f32_16x16x32_bf16(pf, vf, o[j], 0, 0, 0);
      }
    }
    __syncthreads();
  }

  float linv[4];
  #pragma unroll
  for (int t = 0; t < 4; ++t) linv[t] = 1.f / l[t];
  #pragma unroll
  for (int j = 0; j < 4; ++j)
    #pragma unroll
    for (int t = 0; t < 4; ++t) {
      const long row = (long)(b * SEQL + row0 + wid * 16 + g * 4 + t);
      attn[row * DM + h * DH + j * 16 + lc] = f2bf(o[j][t] * linv[t]);
    }
}

// ---------------------------------------------------------------------------
__global__ __launch_bounds__(256) void ln_bf16(const float* __restrict__ x,
    const float* __restrict__ gg, const float* __restrict__ bb, short* __restrict__ out)
{
  int row = blockIdx.x;
  const float4 u = ((const float4*)(x + (long)row * DM))[threadIdx.x];
  float s  = u.x + u.y + u.z + u.w;
  float sq = u.x * u.x + u.y * u.y + u.z * u.z + u.w * u.w;
  #pragma unroll
  for (int o = 32; o; o >>= 1) { s += __shfl_xor(s, o); sq += __shfl_xor(sq, o); }
  __shared__ float red[8];
  int lane = threadIdx.x & 63, wid = threadIdx.x >> 6;
  if (lane == 0) { red[wid] = s; red[4 + wid] = sq; }
  __syncthreads();
  s  = red[0] + red[1] + red[2] + red[3];
  sq = red[4] + red[5] + red[6] + red[7];
  float mu  = s * (1.f / DM);
  float var = fmaxf(sq * (1.f / DM) - mu * mu, 0.f);
  float inv = 1.f / (sqrtf(var) + 1e-6f);
  int c = threadIdx.x * 4;
  const float4 gv = ((const float4*)gg)[threadIdx.x];
  const float4 bv = ((const float4*)bb)[threadIdx.x];
  short4v o;
  o[0] = f2bf((u.x - mu) * inv * gv.x + bv.x);
  o[1] = f2bf((u.y - mu) * inv * gv.y + bv.y);
  o[2] = f2bf((u.z - mu) * inv * gv.z + bv.z);
  o[3] = f2bf((u.w - mu) * inv * gv.w + bv.w);
  *(short4v*)(out + (long)row * DM + c) = o;
}

// ---------------------------------------------------------------------------
__global__ __launch_bounds__(256) void embed_k(const int* __restrict__ toks,
    const float* __restrict__ emb, const float* __restrict__ pos, float* __restrict__ x)
{
  int row = blockIdx.x;
  int s = row & (SEQL - 1);
  long tk = toks[row];
  const float4 e = ((const float4*)(emb + tk * DM))[threadIdx.x];
  const float4 p = ((const float4*)(pos + (long)s * DM))[threadIdx.x];
  float4 o;
  o.x = e.x * 32.f + p.x; o.y = e.y * 32.f + p.y;
  o.z = e.z * 32.f + p.z; o.w = e.w * 32.f + p.w;
  ((float4*)(x + (long)row * DM))[threadIdx.x] = o;
}

// ---------------------------------------------------------------------------
__global__ void wtrans4(const float* __restrict__ Wq, const float* __restrict__ Wk,
                        const float* __restrict__ Wv, const float* __restrict__ Wo,
                        short* __restrict__ Wqkvt, short* __restrict__ Wot)
{
  __shared__ float tile[32][33];
  const int z = blockIdx.z;
  const int w = z / NLAYER, l = z % NLAYER;
  const float* W = (w == 0) ? Wq : (w == 1) ? Wk : (w == 2) ? Wv : Wo;
  const long lo = (long)l * DM * DM;
  short* dst;
  long oo;
  if (w < 3) { dst = Wqkvt; oo = (long)l * 3072 * DM + (long)w * DM * DM; }
  else       { dst = Wot;   oo = (long)l * DM * DM; }
  int n0 = blockIdx.x * 32, k0 = blockIdx.y * 32;
  int tx = threadIdx.x, ty = threadIdx.y;
  #pragma unroll
  for (int i = 0; i < 4; ++i)
    tile[ty + i * 8][tx] = W[lo + (long)(k0 + ty + i * 8) * DM + n0 + tx];
  __syncthreads();
  #pragma unroll
  for (int i = 0; i < 4; ++i)
    dst[oo + (long)(n0 + ty + i * 8) * DM + k0 + tx] = f2bf(tile[tx][ty + i * 8]);
}

// ---------------------------------------------------------------------------
__global__ void wtransF(const float* __restrict__ W1, const float* __restrict__ W2,
                        short* __restrict__ W1t, short* __restrict__ W2t)
{
  __shared__ float tile[32][33];
  const int z = blockIdx.z;
  const int w = z / NLAYER, l = z % NLAYER;
  const int K = w ? DFFN : DM;
  const int N = w ? DM : DFFN;
  const float* W = w ? W2 : W1;
  short* dst = (w ? W2t : W1t);
  const long lo = (long)l * DM * DFFN;
  const long oo = (long)l * DM * DFFN;
  int n0 = (w ? blockIdx.y : blockIdx.x) * 32;
  int k0 = (w ? blockIdx.x : blockIdx.y) * 32;
  int tx = threadIdx.x, ty = threadIdx.y;
  #pragma unroll
  for (int i = 0; i < 4; ++i)
    tile[ty + i * 8][tx] = W[lo + (long)(k0 + ty + i * 8) * N + n0 + tx];
  __syncthreads();
  #pragma unroll
  for (int i = 0; i < 4; ++i)
    dst[oo + (long)(n0 + ty + i * 8) * K + k0 + tx] = f2bf(tile[tx][ty + i * 8]);
}

// ---------------------------------------------------------------------------
__global__ __launch_bounds__(256) void conv_bf16(const float* __restrict__ in,
                                                 short* __restrict__ out)
{
  long i = ((long)blockIdx.x * 256 + threadIdx.x) * 8;
  float4 a = *(const float4*)(in + i);
  float4 b = *(const float4*)(in + i + 4);
  short8 o;
  o[0] = f2bf(a.x); o[1] = f2bf(a.y); o[2] = f2bf(a.z); o[3] = f2bf(a.w);
  o[4] = f2bf(b.x); o[5] = f2bf(b.y); o[6] = f2bf(b.z); o[7] = f2bf(b.w);
  *(short8*)(out + i) = o;
}

// ---------------------------------------------------------------------------
extern "C" void kernel_launch(void* const* d_in, const int* in_sizes, int n_in,
                              void* d_out, int out_size, void* d_ws, size_t ws_size,
                              hipStream_t stream)
{
  (void)in_sizes; (void)n_in; (void)out_size;
  const int*   toks = (const int*)  d_in[0];
  const float* temb = (const float*)d_in[1];
  const float* pemb = (const float*)d_in[2];
  const float* Wq  = (const float*)d_in[3];  const float* bq  = (const float*)d_in[4];
  const float* Wk  = (const float*)d_in[5];  const float* bk  = (const float*)d_in[6];
  const float* Wv  = (const float*)d_in[7];  const float* bv  = (const float*)d_in[8];
  const float* Wo  = (const float*)d_in[9];  const float* bo  = (const float*)d_in[10];
  const float* g1  = (const float*)d_in[11]; const float* be1 = (const float*)d_in[12];
  const float* W1  = (const float*)d_in[13]; const float* bf1 = (const float*)d_in[14];
  const float* W2  = (const float*)d_in[15]; const float* bf2 = (const float*)d_in[16];
  const float* g2  = (const float*)d_in[17]; const float* be2 = (const float*)d_in[18];
  const float* gf  = (const float*)d_in[19]; const float* bfb = (const float*)d_in[20];

  char* p = (char*)d_ws;
  auto carve = [&](size_t bytes) -> char* {
    char* r = p;
    p += (bytes + 255) & ~(size_t)255;
    return r;
  };
  short* h     = (short*)carve((size_t)TOKENS * DM * 2);
  char*  uni   = p;
  short* tembb = (short*)uni;  // bf16 tok_emb overlaps dead weight region at the end
  short* Wqkvt = (short*)carve((size_t)NLAYER * 3072 * DM * 2);
  short* Wot   = (short*)carve((size_t)NLAYER * DM * DM * 2);
  short* W1t   = (short*)carve((size_t)NLAYER * DM * DFFN * 2);
  short* W2t   = (short*)carve((size_t)NLAYER * DM * DFFN * 2);
  float* x     = (float*)carve((size_t)TOKENS * DM * 4);
  short* qkv   = (short*)carve((size_t)TOKENS * 3072 * 2);
  short* attn  = (short*)carve((size_t)TOKENS * DM * 2);
  short* Vt    = (short*)carve((size_t)NBATCH * NHEAD * DH * SEQL * 2);
  short* ffb   = (short*)carve((size_t)TOKENS * DFFN * 2);
  size_t used = (size_t)(p - (char*)d_ws);
  size_t need_t = (size_t)(uni - (char*)d_ws) + (size_t)NVOCAB * DM * 2;
  if (used > ws_size || need_t > ws_size) return;

  dim3 tb(32, 8);

  embed_k<<<TOKENS, 256, 0, stream>>>(toks, temb, pemb, x);
  wtrans4<<<dim3(DM / 32, DM / 32, 4 * NLAYER), tb, 0, stream>>>(Wq, Wk, Wv, Wo, Wqkvt, Wot);
  wtransF<<<dim3(DFFN / 32, DM / 32, 2 * NLAYER), tb, 0, stream>>>(W1, W2, W1t, W2t);

  for (int l = 0; l < NLAYER; ++l) {
    const size_t wqkv = (size_t)l * 3072 * DM;
    const size_t wdd  = (size_t)l * DM * DM;
    const size_t wdf  = (size_t)l * DM * DFFN;
    ln_bf16<<<TOKENS, 256, 0, stream>>>(x, g1 + l * DM, be1 + l * DM, h);
    // QKV with fused V-transpose (vtrans kernel removed)
    launch_gemm<64, 128, 1, 4, 64>(stream, h, Wqkvt + wqkv, qkv,
        bq + l * DM, bk + l * DM, bv + l * DM, nullptr, Vt,
        TOKENS, 3072, DM, DM, DM, 3072, 1.f, FLAG_OUTBF16 | FLAG_VTL);
    flash_attn<<<dim3(SEQL / 64, NBATCH * NHEAD), 256, 0, stream>>>(qkv, Vt, attn);
    launch_gemm<64, 64, 2, 2, 64>(stream, attn, Wot + wdd, x,
        bo + l * DM, nullptr, nullptr, x, nullptr,
        TOKENS, DM, DM, DM, DM, DM, 1.f, 0);
    ln_bf16<<<TOKENS, 256, 0, stream>>>(x, g2 + l * DM, be2 + l * DM, h);
    launch_gemm<128, 128, 2, 2, 64>(stream, h, W1t + wdf, ffb,
        bf1 + l * DFFN, nullptr, nullptr, nullptr, nullptr,
        TOKENS, DFFN, DM, DM, DM, DFFN, 1.f, FLAG_OUTBF16 | FLAG_RELU);
    launch_gemm<64, 64, 2, 2, 64>(stream, ffb, W2t + wdf, x,
        bf2 + l * DM, nullptr, nullptr, x, nullptr,
        TOKENS, DM, DFFN, DFFN, DFFN, DM, 1.f, 0);
  }
  ln_bf16<<<TOKENS, 256, 0, stream>>>(x, gf, bfb, h);
  conv_bf16<<<(NVOCAB * DM) / (256 * 8), 256, 0, stream>>>(temb, tembb);
  {
    dim3 grid(NVOCAB / 256, TOKENS / 256, 1), blk(512);
    gemm256p<<<grid, blk, 0, stream>>>(h, tembb, (float*)d_out, DM, DM, DM, NVOCAB);
  }
}

// Round 20
// 1326.093 us; speedup vs baseline: 1.0238x; 1.0024x over previous
//
#include <hip/hip_runtime.h>

#define TOKENS 2048
#define DM 1024
#define NHEAD 16
#define DH 64
#define SEQL 512
#define NBATCH 4
#define DFFN 4096
#define NLAYER 6
#define NVOCAB 32000

typedef short short8 __attribute__((ext_vector_type(8)));
typedef short short4v __attribute__((ext_vector_type(4)));
typedef float floatx4 __attribute__((ext_vector_type(4)));

#define FLAG_RELU 1
#define FLAG_OUTBF16 2
#define FLAG_VTL 4

#define AS1 __attribute__((address_space(1)))
#define AS3 __attribute__((address_space(3)))

__device__ __forceinline__ float bf2f(short s) {
  unsigned u = ((unsigned)(unsigned short)s) << 16;
  return __builtin_bit_cast(float, u);
}
__device__ __forceinline__ short f2bf(float f) {
  unsigned u = __builtin_bit_cast(unsigned, f);
  u = (u + 0x7FFFu + ((u >> 16) & 1u)) >> 16;
  return (short)(unsigned short)u;
}

template<int N> __device__ __forceinline__ void wait_vm() {
  if constexpr (N == 0)      asm volatile("s_waitcnt vmcnt(0)" ::: "memory");
  else if constexpr (N == 3) asm volatile("s_waitcnt vmcnt(3)" ::: "memory");
  else if constexpr (N == 4) asm volatile("s_waitcnt vmcnt(4)" ::: "memory");
  else if constexpr (N == 6) asm volatile("s_waitcnt vmcnt(6)" ::: "memory");
  else if constexpr (N == 8) asm volatile("s_waitcnt vmcnt(8)" ::: "memory");
  else static_assert(N == 0, "unsupported vmcnt");
}

// ---------------------------------------------------------------------------
// gemm_db v5 (round-10 schedule; round-15 best tile configs; round-19 fused
// V-transpose epilogue). Occupancy rules (r13/r15/r16): >=2 resident
// blocks/CU, grid an even multiple of residency.
// ---------------------------------------------------------------------------
template<int BM, int BN, int WR, int WC, int BK>
__global__ __launch_bounds__(256) void gemm_db(
    const short* __restrict__ A, const short* __restrict__ Bt, void* __restrict__ Cv,
    const float* __restrict__ bias, const float* __restrict__ biask,
    const float* __restrict__ biasv, const float* __restrict__ resid,
    short* __restrict__ vt,
    int K, int lda, int ldb, int ldc, float alpha, int flags)
{
  constexpr int FI = BM / WR / 16;
  constexpr int FJ = BN / WC / 16;
  constexpr int RPI = (BK == 64) ? 32 : 64;
  constexpr int NST = BM / RPI + BN / RPI;
  __shared__ short As[2][BM * BK];
  __shared__ short Bs[2][BN * BK];

  const int gy = gridDim.y;
  int lin = blockIdx.x + gridDim.x * blockIdx.y;
  const int nwg = gridDim.x * gy;
  if ((nwg & 7) == 0) { const int cpx = nwg >> 3; lin = (lin & 7) * cpx + (lin >> 3); }
  const int row0 = (lin % gy) * BM, col0 = (lin / gy) * BN;

  const int tid = threadIdx.x;
  const int lane = tid & 63;
  const int wid = tid >> 6;
  const int wr = wid / WC, wc = wid % WC;
  const int lc = lane & 15, g = lane >> 4;
  const int sr = (BK == 64) ? (tid >> 3) : (tid >> 2);
  const int sc = (BK == 64) ? (tid & 7) : (tid & 3);
  const int swz_s = (BK == 64) ? (sr & 7) : ((sr >> 1) & 3);
  const int scs = (sc ^ swz_s) * 8;

  floatx4 acc[FI][FJ];
  #pragma unroll
  for (int i = 0; i < FI; ++i)
    #pragma unroll
    for (int j = 0; j < FJ; ++j)
      acc[i][j] = (floatx4){0.f, 0.f, 0.f, 0.f};

  auto stage = [&](int k0, int b) {
    char* ad = (char*)As[b];
    char* bd = (char*)Bs[b];
    #pragma unroll
    for (int it = 0; it < BM / RPI; ++it) {
      const short* src = A + (long)(row0 + it * RPI + sr) * lda + k0 + scs;
      __builtin_amdgcn_global_load_lds((const AS1 void*)src,
          (AS3 void*)(ad + it * 4096 + tid * 16), 16, 0, 0);
    }
    #pragma unroll
    for (int it = 0; it < BN / RPI; ++it) {
      const short* src = Bt + (long)(col0 + it * RPI + sr) * ldb + k0 + scs;
      __builtin_amdgcn_global_load_lds((const AS1 void*)src,
          (AS3 void*)(bd + it * 4096 + tid * 16), 16, 0, 0);
    }
  };

  const int NT = K / BK;
  stage(0, 0);
  int cb = 0;
  for (int t = 0; t < NT; ++t) {
    __builtin_amdgcn_s_barrier();
    __builtin_amdgcn_sched_barrier(0);
    if (t + 1 < NT) {
      stage((t + 1) * BK, cb ^ 1);
      wait_vm<NST>();
    } else {
      wait_vm<0>();
    }
    __builtin_amdgcn_sched_barrier(0);

    const short* as = As[cb];
    const short* bs = Bs[cb];
    if constexpr (BK == 64) {
      short8 fa[FI][2], fb[FJ][2];
      #pragma unroll
      for (int i = 0; i < FI; ++i) {
        const int r = wr * (BM / WR) + i * 16 + lc;
        fa[i][0] = *(const short8*)&as[r * 64 + ((g ^ (r & 7)) * 8)];
        fa[i][1] = *(const short8*)&as[r * 64 + (((4 + g) ^ (r & 7)) * 8)];
      }
      #pragma unroll
      for (int j = 0; j < FJ; ++j) {
        const int r = wc * (BN / WC) + j * 16 + lc;
        fb[j][0] = *(const short8*)&bs[r * 64 + ((g ^ (r & 7)) * 8)];
        fb[j][1] = *(const short8*)&bs[r * 64 + (((4 + g) ^ (r & 7)) * 8)];
      }
      #pragma unroll
      for (int i = 0; i < FI; ++i)
        #pragma unroll
        for (int j = 0; j < FJ; ++j) {
          acc[i][j] = __builtin_amdgcn_mfma_f32_16x16x32_bf16(fa[i][0], fb[j][0], acc[i][j], 0, 0, 0);
          acc[i][j] = __builtin_amdgcn_mfma_f32_16x16x32_bf16(fa[i][1], fb[j][1], acc[i][j], 0, 0, 0);
        }
    } else {
      short8 fa[FI], fb[FJ];
      #pragma unroll
      for (int i = 0; i < FI; ++i) {
        const int r = wr * (BM / WR) + i * 16 + lc;
        fa[i] = *(const short8*)&as[r * 32 + ((g ^ ((r >> 1) & 3)) * 8)];
      }
      #pragma unroll
      for (int j = 0; j < FJ; ++j) {
        const int r = wc * (BN / WC) + j * 16 + lc;
        fb[j] = *(const short8*)&bs[r * 32 + ((g ^ ((r >> 1) & 3)) * 8)];
      }
      #pragma unroll
      for (int i = 0; i < FI; ++i)
        #pragma unroll
        for (int j = 0; j < FJ; ++j)
          acc[i][j] = __builtin_amdgcn_mfma_f32_16x16x32_bf16(fa[i], fb[j], acc[i][j], 0, 0, 0);
    }
    cb ^= 1;
  }

  // ---- fused V-transpose epilogue (block-uniform branch) ----
  if ((flags & FLAG_VTL) && col0 >= 2048) {
    __syncthreads();                       // all waves done reading As/Bs
    short* T = (short*)&Bs[0][0];          // [128 c][72] shorts = 18 KB
    #pragma unroll
    for (int i = 0; i < FI; ++i) {
      const int rowl = wr * (BM / WR) + i * 16 + g * 4;   // token-local (t=0)
      #pragma unroll
      for (int j = 0; j < FJ; ++j) {
        const int c  = wc * (BN / WC) + j * 16 + lc;      // V col-local 0..127
        const int bc = col0 + c - 2048;                   // bias index
        short4v o4;
        #pragma unroll
        for (int t = 0; t < 4; ++t)
          o4[t] = f2bf(alpha * acc[i][j][t] + biasv[bc]);
        *(short4v*)&T[c * 72 + rowl] = o4;                // 8B aligned
      }
    }
    __syncthreads();
    const int c = tid & 127, half = tid >> 7;
    const int vcol = col0 - 2048 + c;
    const long dstrow = ((long)(row0 >> 9) * NHEAD + (vcol >> 6)) * DH + (vcol & 63);
    short* dst = vt + dstrow * SEQL + (row0 & (SEQL - 1)) + half * 32;
    const short* src = &T[c * 72 + half * 32];
    #pragma unroll
    for (int k2 = 0; k2 < 4; ++k2)
      *(short8*)(dst + k2 * 8) = *(const short8*)(src + k2 * 8);
    return;
  }

  const bool relu = flags & FLAG_RELU;
  const bool obf  = flags & FLAG_OUTBF16;
  float* Cf = (float*)Cv;
  short* Cb = (short*)Cv;
  #pragma unroll
  for (int i = 0; i < FI; ++i) {
    int orow = row0 + wr * (BM / WR) + i * 16 + g * 4;
    #pragma unroll
    for (int j = 0; j < FJ; ++j) {
      int ocol = col0 + wc * (BN / WC) + j * 16 + lc;
      const float* bp = bias;
      int bc = ocol;
      if (biask && ocol >= 1024) { bp = biask; bc = ocol - 1024; }
      #pragma unroll
      for (int t = 0; t < 4; ++t) {
        long off = (long)(orow + t) * ldc + ocol;
        float v = alpha * acc[i][j][t];
        if (bp)    v += bp[bc];
        if (resid) v += resid[off];
        if (relu)  v = fmaxf(v, 0.f);
        if (obf) Cb[off] = f2bf(v); else Cf[off] = v;
      }
    }
  }
}

template<int BM, int BN, int WR, int WC, int BK>
static inline void launch_gemm(hipStream_t st, const short* A, const short* Bt, void* C,
    const float* bias, const float* biask, const float* biasv, const float* resid,
    short* vt, int M, int N, int K, int lda, int ldb, int ldc, float alpha, int flags)
{
  dim3 grid(N / BN, M / BM, 1), blk(256);
  gemm_db<BM, BN, WR, WC, BK><<<grid, blk, 0, st>>>(A, Bt, C, bias, biask, biasv, resid,
                                                    vt, K, lda, ldb, ldc, alpha, flags);
}

// ---------------------------------------------------------------------------
// gemm256p: head-only 8-phase kernel (unchanged; ~192 us best).
// ---------------------------------------------------------------------------
__global__ __launch_bounds__(512, 2) void gemm256p(
    const short* __restrict__ A, const short* __restrict__ Bt, float* __restrict__ C,
    int K, int lda, int ldb, int ldc)
{
  __shared__ short As[2][2][128 * 64];
  __shared__ short Bs[2][4][64 * 64];

  const int gy = gridDim.y;
  int lin = blockIdx.x + gridDim.x * blockIdx.y;
  const int nwg = gridDim.x * gy;
  if ((nwg & 7) == 0) { const int cpx = nwg >> 3; lin = (lin & 7) * cpx + (lin >> 3); }
  const int row0 = (lin % gy) * 256, col0 = (lin / gy) * 256;

  const int tid = threadIdx.x;
  const int lane = tid & 63;
  const int w = tid >> 6;
  const int wr = w >> 2, wc = w & 3;
  const int lc = lane & 15, g = lane >> 4;
  const int sr = tid >> 3;
  const int sc = tid & 7;
  const int scs = (sc ^ (sr & 7)) * 8;

  floatx4 acc[8][4];
  #pragma unroll
  for (int i = 0; i < 8; ++i)
    #pragma unroll
    for (int j = 0; j < 4; ++j)
      acc[i][j] = (floatx4){0.f, 0.f, 0.f, 0.f};

  auto stageA = [&](int k0, int b, int h) {
    #pragma unroll
    for (int it = 0; it < 2; ++it) {
      const int r = h * 128 + it * 64 + sr;
      const short* src = A + (long)(row0 + r) * lda + k0 + scs;
      __builtin_amdgcn_global_load_lds((const AS1 void*)src,
          (AS3 void*)((char*)&As[b][h][0] + it * 8192 + tid * 16), 16, 0, 0);
    }
  };
  auto stageBq = [&](int k0, int b, int q) {
    const short* src = Bt + (long)(col0 + q * 64 + sr) * ldb + k0 + scs;
    __builtin_amdgcn_global_load_lds((const AS1 void*)src,
        (AS3 void*)((char*)&Bs[b][q][0] + tid * 16), 16, 0, 0);
  };
  auto rdA = [&](int b, int sub, short8 fa[4][2]) {
    const short* base = &As[b][wr][0];
    #pragma unroll
    for (int i = 0; i < 4; ++i) {
      const int r = sub * 64 + i * 16 + lc;
      fa[i][0] = *(const short8*)&base[r * 64 + ((g ^ (r & 7)) * 8)];
      fa[i][1] = *(const short8*)&base[r * 64 + (((4 + g) ^ (r & 7)) * 8)];
    }
  };
  auto rdB = [&](int b, int sub, short8 fb[2][2]) {
    const short* base = &Bs[b][wc][0];
    #pragma unroll
    for (int j = 0; j < 2; ++j) {
      const int r = sub * 32 + j * 16 + lc;
      fb[j][0] = *(const short8*)&base[r * 64 + ((g ^ (r & 7)) * 8)];
      fb[j][1] = *(const short8*)&base[r * 64 + (((4 + g) ^ (r & 7)) * 8)];
    }
  };
  auto mm = [&](short8 fa[4][2], short8 fb[2][2], int io, int jo) {
    #pragma unroll
    for (int i = 0; i < 4; ++i)
      #pragma unroll
      for (int j = 0; j < 2; ++j) {
        floatx4 c = acc[io + i][jo + j];
        c = __builtin_amdgcn_mfma_f32_16x16x32_bf16(fa[i][0], fb[j][0], c, 0, 0, 0);
        c = __builtin_amdgcn_mfma_f32_16x16x32_bf16(fa[i][1], fb[j][1], c, 0, 0, 0);
        acc[io + i][jo + j] = c;
      }
  };

#define PH_SYNC() \
    __builtin_amdgcn_s_barrier(); \
    asm volatile("s_waitcnt lgkmcnt(0)" ::: "memory"); \
    __builtin_amdgcn_sched_barrier(0); \
    __builtin_amdgcn_s_setprio(1);
#define PH_END() \
    __builtin_amdgcn_s_setprio(0); \
    __builtin_amdgcn_s_barrier();

  const int NT = K >> 6;
  stageA(0, 0, 0); stageA(0, 0, 1);
  stageBq(0, 0, 0); stageBq(0, 0, 1); stageBq(0, 0, 2); stageBq(0, 0, 3);
  stageA(64, 1, 0); stageA(64, 1, 1);
  wait_vm<4>();
  __builtin_amdgcn_s_barrier();

  for (int t = 0; t < NT; ++t) {
    const int b = t & 1;
    const int nk = (t + 1) << 6;
    short8 fa[4][2], fb0[2][2], fb1[2][2];
    rdA(b, 0, fa); rdB(b, 0, fb0);
    if (t + 1 < NT) { stageBq(nk, b ^ 1, 0); stageBq(nk, b ^ 1, 1); }
    PH_SYNC();
    mm(fa, fb0, 0, 0);
    PH_END();
    rdB(b, 1, fb1);
    if (t + 1 < NT) { stageBq(nk, b ^ 1, 2); stageBq(nk, b ^ 1, 3); }
    PH_SYNC();
    mm(fa, fb1, 0, 2);
    PH_END();
    rdA(b, 1, fa);
    PH_SYNC();
    mm(fa, fb1, 4, 2);
    PH_END();
    if (t + 2 < NT) {
      stageA((t + 2) << 6, b, 0); stageA((t + 2) << 6, b, 1);
      wait_vm<4>();
    } else {
      wait_vm<0>();
    }
    __builtin_amdgcn_sched_barrier(0);
    __builtin_amdgcn_s_barrier();
    __builtin_amdgcn_s_setprio(1);
    mm(fa, fb0, 4, 0);
    PH_END();
  }
#undef PH_SYNC
#undef PH_END

  #pragma unroll
  for (int i = 0; i < 8; ++i) {
    int orow = row0 + wr * 128 + i * 16 + g * 4;
    #pragma unroll
    for (int j = 0; j < 4; ++j) {
      int ocol = col0 + wc * 64 + j * 16 + lc;
      #pragma unroll
      for (int t = 0; t < 4; ++t)
        C[(long)(orow + t) * ldc + ocol] = acc[i][j][t];
    }
  }
}

// ---------------------------------------------------------------------------
// Flash attention + T13 defer-max. Round-20: XCD-aware (qt,bh) decode — all
// 8 q-tiles of a (b,h) plus 8 distinct bh land on ONE XCD (xcd = lin%8 =
// bh&7), making its K/V (8 x 128 KB = 1 MB) L2-resident instead of being
// refetched by 8 XCDs. Bijective: qt=(lin>>3)&7, bh=(lin>>6)*8+(lin&7).
// ---------------------------------------------------------------------------
__global__ __launch_bounds__(256) void flash_attn(
    const short* __restrict__ qkv, const short* __restrict__ Vt,
    short* __restrict__ attn)
{
  const int lin = blockIdx.y * gridDim.x + blockIdx.x;   // grid (8, 64)
  const int qt = (lin >> 3) & 7;
  const int bh = ((lin >> 6) << 3) | (lin & 7);
  const int b = bh >> 4, h = bh & 15;
  const int row0 = qt * 64;

  __shared__ short Kt[64 * 64];
  __shared__ short Vtl[64 * 64];
  __shared__ short Pt[4 * 16 * 64];

  const int tid = threadIdx.x;
  const int lane = tid & 63;
  const int wid = tid >> 6;
  const int lc = lane & 15, g = lane >> 4;

  short8 qf[2];
  {
    const short* qp = qkv + (long)(b * SEQL + row0 + wid * 16 + lc) * 3072 + h * DH;
    qf[0] = *(const short8*)(qp + g * 8);
    qf[1] = *(const short8*)(qp + 32 + g * 8);
  }

  floatx4 o[4];
  float m[4], l[4];
  #pragma unroll
  for (int j = 0; j < 4; ++j) o[j] = (floatx4){0.f, 0.f, 0.f, 0.f};
  #pragma unroll
  for (int t = 0; t < 4; ++t) { m[t] = -3e38f; l[t] = 0.f; }

  for (int kv0 = 0; kv0 <= row0; kv0 += 64) {
    #pragma unroll
    for (int i = 0; i < 2; ++i) {
      const int idx = i * 256 + tid;
      const int r = idx >> 3, cc = idx & 7;
      const int sw = cc ^ (r & 7);
      const short* ks = qkv + (long)(b * SEQL + kv0 + r) * 3072 + 1024 + h * DH + sw * 8;
      __builtin_amdgcn_global_load_lds((const AS1 void*)ks,
          (AS3 void*)((char*)Kt + (i * 256 + wid * 64) * 16), 16, 0, 0);
      const short* vs = Vt + (long)bh * DH * SEQL + (long)r * SEQL + kv0 + sw * 8;
      __builtin_amdgcn_global_load_lds((const AS1 void*)vs,
          (AS3 void*)((char*)Vtl + (i * 256 + wid * 64) * 16), 16, 0, 0);
    }
    __syncthreads();

    floatx4 s[4];
    #pragma unroll
    for (int j = 0; j < 4; ++j) s[j] = (floatx4){0.f, 0.f, 0.f, 0.f};
    #pragma unroll
    for (int ks_ = 0; ks_ < 2; ++ks_) {
      #pragma unroll
      for (int j = 0; j < 4; ++j) {
        const int row = j * 16 + lc;
        const short8 kf = *(const short8*)&Kt[row * 64 + ((ks_ * 4 + g) ^ (row & 7)) * 8];
        s[j] = __builtin_amdgcn_mfma_f32_16x16x32_bf16(qf[ks_], kf, s[j], 0, 0, 0);
      }
    }

    const bool diag = (kv0 == row0);
    float p[4][4], rmax[4], rsum[4];
    #pragma unroll
    for (int t = 0; t < 4; ++t) rmax[t] = -3e38f;
    #pragma unroll
    for (int j = 0; j < 4; ++j)
      #pragma unroll
      for (int t = 0; t < 4; ++t) {
        float sv = s[j][t] * 0.125f;
        if (diag && (j * 16 + lc) > (wid * 16 + g * 4 + t)) sv = -3e38f;
        p[j][t] = sv;
        rmax[t] = fmaxf(rmax[t], sv);
      }
    #pragma unroll
    for (int t = 0; t < 4; ++t) {
      #pragma unroll
      for (int mk = 1; mk < 16; mk <<= 1)
        rmax[t] = fmaxf(rmax[t], __shfl_xor(rmax[t], mk));
    }
    bool need = (rmax[0] > m[0] + 8.f) || (rmax[1] > m[1] + 8.f) ||
                (rmax[2] > m[2] + 8.f) || (rmax[3] > m[3] + 8.f);
    if (__any(need)) {
      float fs[4];
      #pragma unroll
      for (int t = 0; t < 4; ++t) {
        float mn = fmaxf(m[t], rmax[t]);
        fs[t] = __expf(m[t] - mn);
        m[t] = mn;
        l[t] *= fs[t];
      }
      #pragma unroll
      for (int j = 0; j < 4; ++j) {
        o[j][0] *= fs[0]; o[j][1] *= fs[1]; o[j][2] *= fs[2]; o[j][3] *= fs[3];
      }
    }
    #pragma unroll
    for (int j = 0; j < 4; ++j)
      #pragma unroll
      for (int t = 0; t < 4; ++t)
        p[j][t] = __expf(p[j][t] - m[t]);
    #pragma unroll
    for (int t = 0; t < 4; ++t) {
      rsum[t] = p[0][t] + p[1][t] + p[2][t] + p[3][t];
      #pragma unroll
      for (int mk = 1; mk < 16; mk <<= 1)
        rsum[t] += __shfl_xor(rsum[t], mk);
      l[t] += rsum[t];
    }
    #pragma unroll
    for (int j = 0; j < 4; ++j)
      #pragma unroll
      for (int t = 0; t < 4; ++t) {
        const int r = g * 4 + t;
        const int col = j * 16 + lc;
        Pt[wid * 1024 + r * 64 + (((col >> 3) ^ (r & 7)) * 8) + (col & 7)] = f2bf(p[j][t]);
      }
    __syncthreads();

    #pragma unroll
    for (int ks_ = 0; ks_ < 2; ++ks_) {
      const short8 pf = *(const short8*)&Pt[wid * 1024 + lc * 64 + ((ks_ * 4 + g) ^ (lc & 7)) * 8];
      #pragma unroll
      for (int j = 0; j < 4; ++j) {
        const int row = j * 16 + lc;
        const short8 vf = *(const short8*)&Vtl[row * 64 + ((ks_ * 4 + g) ^ (row & 7)) * 8];
        o[j] = __builtin_amdgcn_mfma_f32_16x16x32_bf16(pf, vf, o[j], 0, 0, 0);
      }
    }
    __syncthreads();
  }

  float linv[4];
  #pragma unroll
  for (int t = 0; t < 4; ++t) linv[t] = 1.f / l[t];
  #pragma unroll
  for (int j = 0; j < 4; ++j)
    #pragma unroll
    for (int t = 0; t < 4; ++t) {
      const long row = (long)(b * SEQL + row0 + wid * 16 + g * 4 + t);
      attn[row * DM + h * DH + j * 16 + lc] = f2bf(o[j][t] * linv[t]);
    }
}

// ---------------------------------------------------------------------------
__global__ __launch_bounds__(256) void ln_bf16(const float* __restrict__ x,
    const float* __restrict__ gg, const float* __restrict__ bb, short* __restrict__ out)
{
  int row = blockIdx.x;
  const float4 u = ((const float4*)(x + (long)row * DM))[threadIdx.x];
  float s  = u.x + u.y + u.z + u.w;
  float sq = u.x * u.x + u.y * u.y + u.z * u.z + u.w * u.w;
  #pragma unroll
  for (int o = 32; o; o >>= 1) { s += __shfl_xor(s, o); sq += __shfl_xor(sq, o); }
  __shared__ float red[8];
  int lane = threadIdx.x & 63, wid = threadIdx.x >> 6;
  if (lane == 0) { red[wid] = s; red[4 + wid] = sq; }
  __syncthreads();
  s  = red[0] + red[1] + red[2] + red[3];
  sq = red[4] + red[5] + red[6] + red[7];
  float mu  = s * (1.f / DM);
  float var = fmaxf(sq * (1.f / DM) - mu * mu, 0.f);
  float inv = 1.f / (sqrtf(var) + 1e-6f);
  int c = threadIdx.x * 4;
  const float4 gv = ((const float4*)gg)[threadIdx.x];
  const float4 bv = ((const float4*)bb)[threadIdx.x];
  short4v o;
  o[0] = f2bf((u.x - mu) * inv * gv.x + bv.x);
  o[1] = f2bf((u.y - mu) * inv * gv.y + bv.y);
  o[2] = f2bf((u.z - mu) * inv * gv.z + bv.z);
  o[3] = f2bf((u.w - mu) * inv * gv.w + bv.w);
  *(short4v*)(out + (long)row * DM + c) = o;
}

// ---------------------------------------------------------------------------
__global__ __launch_bounds__(256) void embed_k(const int* __restrict__ toks,
    const float* __restrict__ emb, const float* __restrict__ pos, float* __restrict__ x)
{
  int row = blockIdx.x;
  int s = row & (SEQL - 1);
  long tk = toks[row];
  const float4 e = ((const float4*)(emb + tk * DM))[threadIdx.x];
  const float4 p = ((const float4*)(pos + (long)s * DM))[threadIdx.x];
  float4 o;
  o.x = e.x * 32.f + p.x; o.y = e.y * 32.f + p.y;
  o.z = e.z * 32.f + p.z; o.w = e.w * 32.f + p.w;
  ((float4*)(x + (long)row * DM))[threadIdx.x] = o;
}

// ---------------------------------------------------------------------------
__global__ void wtrans4(const float* __restrict__ Wq, const float* __restrict__ Wk,
                        const float* __restrict__ Wv, const float* __restrict__ Wo,
                        short* __restrict__ Wqkvt, short* __restrict__ Wot)
{
  __shared__ float tile[32][33];
  const int z = blockIdx.z;
  const int w = z / NLAYER, l = z % NLAYER;
  const float* W = (w == 0) ? Wq : (w == 1) ? Wk : (w == 2) ? Wv : Wo;
  const long lo = (long)l * DM * DM;
  short* dst;
  long oo;
  if (w < 3) { dst = Wqkvt; oo = (long)l * 3072 * DM + (long)w * DM * DM; }
  else       { dst = Wot;   oo = (long)l * DM * DM; }
  int n0 = blockIdx.x * 32, k0 = blockIdx.y * 32;
  int tx = threadIdx.x, ty = threadIdx.y;
  #pragma unroll
  for (int i = 0; i < 4; ++i)
    tile[ty + i * 8][tx] = W[lo + (long)(k0 + ty + i * 8) * DM + n0 + tx];
  __syncthreads();
  #pragma unroll
  for (int i = 0; i < 4; ++i)
    dst[oo + (long)(n0 + ty + i * 8) * DM + k0 + tx] = f2bf(tile[tx][ty + i * 8]);
}

// ---------------------------------------------------------------------------
__global__ void wtransF(const float* __restrict__ W1, const float* __restrict__ W2,
                        short* __restrict__ W1t, short* __restrict__ W2t)
{
  __shared__ float tile[32][33];
  const int z = blockIdx.z;
  const int w = z / NLAYER, l = z % NLAYER;
  const int K = w ? DFFN : DM;
  const int N = w ? DM : DFFN;
  const float* W = w ? W2 : W1;
  short* dst = (w ? W2t : W1t);
  const long lo = (long)l * DM * DFFN;
  const long oo = (long)l * DM * DFFN;
  int n0 = (w ? blockIdx.y : blockIdx.x) * 32;
  int k0 = (w ? blockIdx.x : blockIdx.y) * 32;
  int tx = threadIdx.x, ty = threadIdx.y;
  #pragma unroll
  for (int i = 0; i < 4; ++i)
    tile[ty + i * 8][tx] = W[lo + (long)(k0 + ty + i * 8) * N + n0 + tx];
  __syncthreads();
  #pragma unroll
  for (int i = 0; i < 4; ++i)
    dst[oo + (long)(n0 + ty + i * 8) * K + k0 + tx] = f2bf(tile[tx][ty + i * 8]);
}

// ---------------------------------------------------------------------------
__global__ __launch_bounds__(256) void conv_bf16(const float* __restrict__ in,
                                                 short* __restrict__ out)
{
  long i = ((long)blockIdx.x * 256 + threadIdx.x) * 8;
  float4 a = *(const float4*)(in + i);
  float4 b = *(const float4*)(in + i + 4);
  short8 o;
  o[0] = f2bf(a.x); o[1] = f2bf(a.y); o[2] = f2bf(a.z); o[3] = f2bf(a.w);
  o[4] = f2bf(b.x); o[5] = f2bf(b.y); o[6] = f2bf(b.z); o[7] = f2bf(b.w);
  *(short8*)(out + i) = o;
}

// ---------------------------------------------------------------------------
extern "C" void kernel_launch(void* const* d_in, const int* in_sizes, int n_in,
                              void* d_out, int out_size, void* d_ws, size_t ws_size,
                              hipStream_t stream)
{
  (void)in_sizes; (void)n_in; (void)out_size;
  const int*   toks = (const int*)  d_in[0];
  const float* temb = (const float*)d_in[1];
  const float* pemb = (const float*)d_in[2];
  const float* Wq  = (const float*)d_in[3];  const float* bq  = (const float*)d_in[4];
  const float* Wk  = (const float*)d_in[5];  const float* bk  = (const float*)d_in[6];
  const float* Wv  = (const float*)d_in[7];  const float* bv  = (const float*)d_in[8];
  const float* Wo  = (const float*)d_in[9];  const float* bo  = (const float*)d_in[10];
  const float* g1  = (const float*)d_in[11]; const float* be1 = (const float*)d_in[12];
  const float* W1  = (const float*)d_in[13]; const float* bf1 = (const float*)d_in[14];
  const float* W2  = (const float*)d_in[15]; const float* bf2 = (const float*)d_in[16];
  const float* g2  = (const float*)d_in[17]; const float* be2 = (const float*)d_in[18];
  const float* gf  = (const float*)d_in[19]; const float* bfb = (const float*)d_in[20];

  char* p = (char*)d_ws;
  auto carve = [&](size_t bytes) -> char* {
    char* r = p;
    p += (bytes + 255) & ~(size_t)255;
    return r;
  };
  short* h     = (short*)carve((size_t)TOKENS * DM * 2);
  char*  uni   = p;
  short* tembb = (short*)uni;  // bf16 tok_emb overlaps dead weight region at the end
  short* Wqkvt = (short*)carve((size_t)NLAYER * 3072 * DM * 2);
  short* Wot   = (short*)carve((size_t)NLAYER * DM * DM * 2);
  short* W1t   = (short*)carve((size_t)NLAYER * DM * DFFN * 2);
  short* W2t   = (short*)carve((size_t)NLAYER * DM * DFFN * 2);
  float* x     = (float*)carve((size_t)TOKENS * DM * 4);
  short* qkv   = (short*)carve((size_t)TOKENS * 3072 * 2);
  short* attn  = (short*)carve((size_t)TOKENS * DM * 2);
  short* Vt    = (short*)carve((size_t)NBATCH * NHEAD * DH * SEQL * 2);
  short* ffb   = (short*)carve((size_t)TOKENS * DFFN * 2);
  size_t used = (size_t)(p - (char*)d_ws);
  size_t need_t = (size_t)(uni - (char*)d_ws) + (size_t)NVOCAB * DM * 2;
  if (used > ws_size || need_t > ws_size) return;

  dim3 tb(32, 8);

  embed_k<<<TOKENS, 256, 0, stream>>>(toks, temb, pemb, x);
  wtrans4<<<dim3(DM / 32, DM / 32, 4 * NLAYER), tb, 0, stream>>>(Wq, Wk, Wv, Wo, Wqkvt, Wot);
  wtransF<<<dim3(DFFN / 32, DM / 32, 2 * NLAYER), tb, 0, stream>>>(W1, W2, W1t, W2t);

  for (int l = 0; l < NLAYER; ++l) {
    const size_t wqkv = (size_t)l * 3072 * DM;
    const size_t wdd  = (size_t)l * DM * DM;
    const size_t wdf  = (size_t)l * DM * DFFN;
    ln_bf16<<<TOKENS, 256, 0, stream>>>(x, g1 + l * DM, be1 + l * DM, h);
    launch_gemm<64, 128, 1, 4, 64>(stream, h, Wqkvt + wqkv, qkv,
        bq + l * DM, bk + l * DM, bv + l * DM, nullptr, Vt,
        TOKENS, 3072, DM, DM, DM, 3072, 1.f, FLAG_OUTBF16 | FLAG_VTL);
    flash_attn<<<dim3(SEQL / 64, NBATCH * NHEAD), 256, 0, stream>>>(qkv, Vt, attn);
    launch_gemm<64, 64, 2, 2, 64>(stream, attn, Wot + wdd, x,
        bo + l * DM, nullptr, nullptr, x, nullptr,
        TOKENS, DM, DM, DM, DM, DM, 1.f, 0);
    ln_bf16<<<TOKENS, 256, 0, stream>>>(x, g2 + l * DM, be2 + l * DM, h);
    launch_gemm<128, 128, 2, 2, 64>(stream, h, W1t + wdf, ffb,
        bf1 + l * DFFN, nullptr, nullptr, nullptr, nullptr,
        TOKENS, DFFN, DM, DM, DM, DFFN, 1.f, FLAG_OUTBF16 | FLAG_RELU);
    launch_gemm<64, 64, 2, 2, 64>(stream, ffb, W2t + wdf, x,
        bf2 + l * DM, nullptr, nullptr, x, nullptr,
        TOKENS, DM, DFFN, DFFN, DFFN, DM, 1.f, 0);
  }
  ln_bf16<<<TOKENS, 256, 0, stream>>>(x, gf, bfb, h);
  conv_bf16<<<(NVOCAB * DM) / (256 * 8), 256, 0, stream>>>(temb, tembb);
  {
    dim3 grid(NVOCAB / 256, TOKENS / 256, 1), blk(512);
    gemm256p<<<grid, blk, 0, stream>>>(h, tembb, (float*)d_out, DM, DM, DM, NVOCAB);
  }
}